// Round 6
// baseline (1973.875 us; speedup 1.0000x reference)
//
#include <hip/hip_runtime.h>
#include <stdint.h>
#include <stddef.h>

typedef short bf16x8 __attribute__((ext_vector_type(8)));
typedef float f32x4  __attribute__((ext_vector_type(4)));
typedef unsigned short ushort_t;

#define H_ 256
#define W_ 448
#define HP_ 258
#define WP_ 450
#define NPIX (H_*W_)
#define PPLANE (HP_*WP_)

// ---------------- workspace layout (bytes) ----------------
#define XPAD_OFF 0ull
#define XPAD_CB_STRIDE ((size_t)2*PPLANE*16)      // 3,715,200 per ci-block of 8
#define XPAD_CB_STRIDE32 (3715200u)
#define XPAD_SIZE ((size_t)64*XPAD_CB_STRIDE)     // 237,772,800
#define FPAD_OFF (XPAD_OFF + XPAD_SIZE)
#define FPAD_SIZE ((size_t)2*PPLANE*16)           // 3,715,200
#define WT_OFF   (FPAD_OFF + FPAD_SIZE)
#define WT_SIZE  ((size_t)256*9*512*2)            // 2,359,296
#define WTF_OFF  (WT_OFF + WT_SIZE)
#define WTF_SIZE ((size_t)256*128*2)              // 65,536
#define WS_NEEDED (WTF_OFF + WTF_SIZE)

__device__ __forceinline__ ushort_t bf16r(float f){
  union { float f; uint32_t u; } c; c.f = f;
  uint32_t u = c.u;
  return (ushort_t)((u + 0x7FFFu + ((u >> 16) & 1u)) >> 16);
}

// ---------------- prep: features -> padded NHWC-blocked bf16 ----------------
__global__ void prep_x(const float* __restrict__ feat, uint8_t* __restrict__ ws){
  int blk = blockIdx.x;
  int yp = blk % HP_;
  int t  = blk / HP_;
  int b  = t & 1;
  int cb = t >> 1;
  uint8_t* dst = ws + XPAD_OFF + (size_t)(cb*2 + b)*((size_t)PPLANE*16) + (size_t)yp*WP_*16;
  bool inrow = (yp >= 1 && yp <= H_);
  const float* src0 = feat + ((size_t)b*512 + (size_t)cb*8)*((size_t)H_*W_) + (size_t)(yp-1)*W_;
  for(int xp = threadIdx.x; xp < WP_; xp += blockDim.x){
    union { ushort_t u[8]; uint4 q; } v;
    if(inrow && xp >= 1 && xp <= W_){
      int x = xp - 1;
      #pragma unroll
      for(int r = 0; r < 8; r++) v.u[r] = bf16r(src0[(size_t)r*H_*W_ + x]);
    } else {
      v.q = make_uint4(0,0,0,0);
    }
    *(uint4*)(dst + (size_t)xp*16) = v.q;
  }
}

// ---------------- prep: flows -> padded NHWC bf16 (8 ch records) ----------------
__global__ void prep_f(const float* __restrict__ init_flow, const float* __restrict__ flow_fix,
                       uint8_t* __restrict__ ws){
  int blk = blockIdx.x;
  int yp = blk % HP_;
  int b  = blk / HP_;
  uint8_t* dst = ws + FPAD_OFF + ((size_t)b*PPLANE + (size_t)yp*WP_)*16;
  for(int xp = threadIdx.x; xp < WP_; xp += blockDim.x){
    union { ushort_t u[8]; uint4 q; } v;
    if(yp >= 1 && yp <= H_ && xp >= 1 && xp <= W_){
      int y = yp - 1, x = xp - 1;
      #pragma unroll
      for(int r = 0; r < 4; r++) v.u[r]   = bf16r(init_flow[(((size_t)b*4 + r)*H_ + y)*W_ + x]);
      #pragma unroll
      for(int r = 0; r < 4; r++) v.u[4+r] = bf16r(flow_fix [(((size_t)b*4 + r)*H_ + y)*W_ + x]);
    } else {
      v.q = make_uint4(0,0,0,0);
    }
    *(uint4*)(dst + (size_t)xp*16) = v.q;
  }
}

// ---------------- prep: weights -> bf16, K-contiguous layouts ----------------
__global__ void prep_w(const float* __restrict__ w1, uint8_t* __restrict__ ws){
  int idx = blockIdx.x*256 + threadIdx.x;
  ushort_t* wt  = (ushort_t*)(ws + WT_OFF);
  ushort_t* wtf = (ushort_t*)(ws + WTF_OFF);
  if(idx < 256*9*512){
    int co  = idx / (9*512);
    int rem = idx % (9*512);
    int s   = rem / 512;
    int ci  = rem % 512;
    float v = w1[((size_t)co*520 + 8 + ci)*9 + s];
    wt[((size_t)co*9 + s)*512 + ci] = bf16r(v);
  } else {
    int i2 = idx - 256*9*512;
    if(i2 < 256*128){
      int co = i2 >> 7;
      int k  = i2 & 127;
      float v = 0.f;
      if(k < 64){ int s = k >> 3, c = k & 7; v = w1[((size_t)co*520 + c)*9 + s]; }
      else if(k < 72){ int c = k - 64;       v = w1[((size_t)co*520 + c)*9 + 8]; }
      wtf[co*128 + k] = bf16r(v);
    }
  }
}

// ---------------- fused conv3x3 + PReLU + conv1x1 + softmax + merge ----------------
// BM=256, BN=256, BK=64. 8 waves (2M x 4N), wave tile 128x64, acc[8][4].
// m201-style 8-phase/tile-pair: each phase reads NEXT quadrant's fragments into
// the alternate register set, MFMAs the current quadrant from the set read last
// phase, issues 2 staging gloads, then ONE barrier. vmcnt(2) at ph2/ph6 only.
#define TILEBUF 65536
#define MASK_OFF 65536
#define W2_OFF   90112
#define SMEM_TOTAL 131072

__device__ __forceinline__ void gload16(const uint8_t* g, uint8_t* l){
  __builtin_amdgcn_global_load_lds((const __attribute__((address_space(1))) uint32_t*)g,
                                   (__attribute__((address_space(3))) uint32_t*)l, 16, 0, 0);
}
__device__ __forceinline__ void bar(){
  asm volatile("" ::: "memory");
  __builtin_amdgcn_s_barrier();
  asm volatile("" ::: "memory");
}
__device__ __forceinline__ void bar_lds(){
  asm volatile("s_waitcnt lgkmcnt(0)" ::: "memory");
  __builtin_amdgcn_s_barrier();
  asm volatile("" ::: "memory");
}

// one phase: reads for next quadrant -> staging -> MFMA current quadrant -> vm -> bar
// vmn: -1 none; 2 -> vmcnt(2); 9 -> full?vmcnt(2):vmcnt(0)
#define PHASE(accbase, avu, bvu, rbuf, rmh, rkc, avd, dobv, bvd, vmn, ...)            \
  {                                                                                    \
    const uint8_t* Ab_ = (rbuf);                                                       \
    _Pragma("unroll")                                                                  \
    for(int mi = 0; mi < 4; mi++)                                                      \
      avd[mi] = *(const bf16x8*)(Ab_ + ((rowA0 + (uint32_t)((rmh)*8192 + mi*2048 + (rkc)*64) + koff) ^ sw)); \
    if(dobv){                                                                          \
      _Pragma("unroll")                                                                \
      for(int ni = 0; ni < 4; ni++)                                                    \
        bvd[ni] = *(const bf16x8*)(Ab_ + 32768 + ((rowB0 + (uint32_t)(ni*2048 + (rkc)*64) + koff) ^ sw)); \
    }                                                                                  \
    __VA_ARGS__;                                                                       \
    __builtin_amdgcn_s_setprio(1);                                                     \
    _Pragma("unroll")                                                                  \
    for(int ni = 0; ni < 4; ni++){                                                     \
      _Pragma("unroll")                                                                \
      for(int mi = 0; mi < 4; mi++)                                                    \
        acc[(accbase)+mi][ni] = __builtin_amdgcn_mfma_f32_16x16x32_bf16(avu[mi], bvu[ni], acc[(accbase)+mi][ni], 0, 0, 0); \
    }                                                                                  \
    __builtin_amdgcn_s_setprio(0);                                                     \
    if((vmn) == 2)      asm volatile("s_waitcnt vmcnt(2)" ::: "memory");               \
    else if((vmn) == 9){                                                               \
      if(full) asm volatile("s_waitcnt vmcnt(2)" ::: "memory");                        \
      else     asm volatile("s_waitcnt vmcnt(0)" ::: "memory");                        \
    }                                                                                  \
    asm volatile("" ::: "memory");                                                     \
    __builtin_amdgcn_s_barrier();                                                      \
    asm volatile("" ::: "memory");                                                     \
  }

__launch_bounds__(512, 2)
__global__ void mega(const uint8_t* __restrict__ ws, const float* __restrict__ w2,
                     const float* __restrict__ b1, const float* __restrict__ pw,
                     const float* __restrict__ b2,
                     const float* __restrict__ init_flow, const float* __restrict__ flow_fix,
                     float* __restrict__ out){
  __shared__ uint8_t smem[SMEM_TOTAL];
  const int tid = threadIdx.x;
  const int l   = tid & 63;
  const int w   = tid >> 6;
  // T1: XCD-aware bijective swizzle (896 = 8 * 112)
  const int blk0 = blockIdx.x;
  const int blk  = (blk0 & 7)*112 + (blk0 >> 3);
  const int b   = blk / 448;
  const int p0  = (blk % 448) * 256;

  // --- per-lane staging precompute (inverse-swizzled source addressing) ---
  uint32_t aoff[4], foff72[4], foff73[4], boff[4], bfl[4];
  #pragma unroll
  for(int q = 0; q < 4; q++){
    uint32_t P = (uint32_t)(q*8192 + tid*16);
    uint32_t L = P ^ (((P >> 7) & 7u) << 4);
    int m  = (int)(L >> 7);           // 0..255 pixel row
    int cb = (int)((L >> 4) & 7u);    // ci-block within row
    int p  = p0 + m;
    int y  = p / W_, x = p - y*W_;
    int pixoff = (y + 1)*WP_ + (x + 1);
    aoff[q] = (uint32_t)cb*XPAD_CB_STRIDE32 + (uint32_t)(b*(PPLANE*16)) + (uint32_t)(pixoff*16);
    int dy = cb/3, dx = cb - dy*3;
    foff72[q] = (uint32_t)((b*PPLANE + pixoff + (dy-1)*WP_ + (dx-1))*16);
    foff73[q] = (cb == 0) ? (uint32_t)((b*PPLANE + pixoff + WP_ + 1)*16) : 0u;
  }
  #pragma unroll
  for(int r = 0; r < 4; r++){
    uint32_t P = (uint32_t)(r*8192 + tid*16);
    uint32_t L = P ^ (((P >> 7) & 7u) << 4);
    uint32_t co = L >> 7, cib = L & 127u;
    boff[r] = co*9216u + cib;
    bfl[r]  = co*256u + cib;
  }

  const uint8_t* xpad = ws + XPAD_OFF;
  const uint8_t* fpad = ws + FPAD_OFF;
  const uint8_t* wt   = ws + WT_OFF;
  const uint8_t* wtf  = ws + WTF_OFF;

  // fragment-read per-lane constants
  const int wave_m = w >> 2, wave_n = w & 3;
  const uint32_t koff = ((uint32_t)(l >> 4))*16u;
  const uint32_t sw   = ((uint32_t)(l & 7)) << 4;
  const uint32_t rowA0 = ((uint32_t)(wave_m*128 + (l & 15)))*128u;
  const uint32_t rowB0 = ((uint32_t)(wave_n*64  + (l & 15)))*128u;

  const uint8_t* B0 = smem;
  const uint8_t* B1 = smem + TILEBUF;

  const f32x4 zero4 = {0.f, 0.f, 0.f, 0.f};
  f32x4 acc[8][4];
  #pragma unroll
  for(int i = 0; i < 8; i++)
    #pragma unroll
    for(int j = 0; j < 4; j++) acc[i][j] = zero4;

  // stage chunk-pairs: A chunks {c0,c0+1} / B chunks {c0,c0+1} of tile tn into buf nb
  auto stA = [&](int tn, uint32_t nb, int c0){
    uint8_t* la = smem + nb*TILEBUF + (uint32_t)(c0*8192) + (uint32_t)(tid*16);
    if(tn < 72){
      int s = tn >> 3, kk = tn & 7;
      int dy = s/3, dx = s - dy*3;
      uint32_t stepA = (uint32_t)(kk*8)*XPAD_CB_STRIDE32 + (uint32_t)(((dy-1)*WP_ + (dx-1))*16);
      gload16(xpad + (aoff[c0]   + stepA), la);
      gload16(xpad + (aoff[c0+1] + stepA), la + 8192);
    } else if(tn == 72){
      gload16(fpad + foff72[c0],   la);
      gload16(fpad + foff72[c0+1], la + 8192);
    } else {
      gload16(fpad + foff73[c0],   la);
      gload16(fpad + foff73[c0+1], la + 8192);
    }
  };
  auto stB = [&](int tn, uint32_t nb, int c0){
    uint8_t* lb = smem + nb*TILEBUF + 32768u + (uint32_t)(c0*8192) + (uint32_t)(tid*16);
    if(tn < 72){
      int s = tn >> 3, kk = tn & 7;
      uint32_t stepB = (uint32_t)(s*1024 + kk*128);
      gload16(wt + (boff[c0]   + stepB), lb);
      gload16(wt + (boff[c0+1] + stepB), lb + 8192);
    } else if(tn == 72){
      gload16(wtf + bfl[c0],   lb);
      gload16(wtf + bfl[c0+1], lb + 8192);
    } else {
      gload16(wtf + (bfl[c0]   + 128u), lb);
      gload16(wtf + (bfl[c0+1] + 128u), lb + 8192);
    }
  };

  bf16x8 avA[4], avB[4], bvA[4], bvB[4];

  // prologue: stage A0,B0,A1 (12 loads); retire A0,B0; pre-read q0(tile0)
  stA(0, 0, 0); stA(0, 0, 2);
  stB(0, 0, 0); stB(0, 0, 2);
  stA(1, 1, 0); stA(1, 1, 2);
  asm volatile("s_waitcnt vmcnt(4)" ::: "memory");
  bar();
  #pragma unroll
  for(int mi = 0; mi < 4; mi++)
    avA[mi] = *(const bf16x8*)(B0 + ((rowA0 + (uint32_t)(mi*2048) + koff) ^ sw));
  #pragma unroll
  for(int ni = 0; ni < 4; ni++)
    bvA[ni] = *(const bf16x8*)(B0 + 32768 + ((rowB0 + (uint32_t)(ni*2048) + koff) ^ sw));

  #pragma unroll 1
  for(int i = 0; i < 37; i++){
    const int e = 2*i;
    const bool full = (i < 36);
    // ph0: MFMA e.q0(mh0,kc0) | read e.q1(mh1,kc0)->avB | stage B(e+1)ch01
    PHASE(0, avA, bvA, B0, 1, 0, avB, false, bvB, -1, { stB(e+1, 1, 0); });
    // ph1: MFMA e.q1 | read e.q2(mh0,kc1)->avA,bvB | stage B(e+1)ch23
    PHASE(4, avB, bvA, B0, 0, 1, avA, true,  bvB, -1, { stB(e+1, 1, 2); });
    // ph2: MFMA e.q2 | read e.q3(mh1,kc1)->avB | stage A(e+2)ch01 | vmcnt
    PHASE(0, avA, bvB, B0, 1, 1, avB, false, bvA,  9, { if(full) stA(e+2, 0, 0); });
    // ph3: MFMA e.q3 | read o.q0(mh0,kc0)->avA,bvA (buf1) | stage A(e+2)ch23
    PHASE(4, avB, bvB, B1, 0, 0, avA, true,  bvA, -1, { if(full) stA(e+2, 0, 2); });
    // ph4: MFMA o.q0 | read o.q1->avB | stage B(e+2)ch01
    PHASE(0, avA, bvA, B1, 1, 0, avB, false, bvB, -1, { if(full) stB(e+2, 0, 0); });
    // ph5: MFMA o.q1 | read o.q2->avA,bvB | stage B(e+2)ch23
    PHASE(4, avB, bvA, B1, 0, 1, avA, true,  bvB, -1, { if(full) stB(e+2, 0, 2); });
    // ph6: MFMA o.q2 | read o.q3->avB | stage A(e+3)ch01 | vmcnt(2)
    PHASE(0, avA, bvB, B1, 1, 1, avB, false, bvA,  2, { if(full) stA(e+3, 1, 0); });
    // ph7: MFMA o.q3 | read e'.q0(buf0)->avA,bvA | stage A(e+3)ch23
    PHASE(4, avB, bvB, B0, 0, 0, avA, true,  bvA, -1, { if(full) stA(e+3, 1, 2); });
  }

  // --- stage W2 (fp32 -> bf16) into LDS, rows of 512B, XOR-swizzled ---
  for(int e2 = tid; e2 < 48*256; e2 += 512){
    int row = e2 >> 8, k = e2 & 255;
    float f = (row < 36) ? w2[row*256 + k] : 0.f;
    uint32_t phys = ((uint32_t)(row*512 + k*2)) ^ (((uint32_t)(row & 7)) << 4);
    *(ushort_t*)(smem + W2_OFF + phys) = bf16r(f);
  }

  // --- epilogue: two passes of 128 pixels each ---
  #pragma unroll
  for(int pass = 0; pass < 2; pass++){
    if(pass) bar();   // pass-0 softmax/merge done before overwriting x-half & mask
    if(wave_m == pass){
      #pragma unroll
      for(int ni = 0; ni < 4; ni++){
        int co = wave_n*64 + ni*16 + (l & 15);
        float bb = b1[co];
        float pp = pw[co];
        #pragma unroll
        for(int mi = 0; mi < 8; mi++){
          #pragma unroll
          for(int j = 0; j < 4; j++){
            float v = acc[mi][ni][j] + bb;
            v = (v < 0.f) ? v*pp : v;
            int px = mi*16 + ((l >> 4) << 2) + j;     // 0..127 within the pass
            uint32_t phys = ((uint32_t)(px*512 + co*2)) ^ (((uint32_t)(px & 7)) << 4);
            *(ushort_t*)(smem + phys) = bf16r(v);
          }
        }
      }
    }
    bar_lds();   // x-half (and W2 on pass 0) visible to all

    // mask GEMM: wave w -> pixel rows [16w, 16w+16), N=48 (36 valid), K=256
    f32x4 acc2[3];
    #pragma unroll
    for(int ni = 0; ni < 3; ni++) acc2[ni] = zero4;
    {
      const uint32_t rowX = ((uint32_t)(16*w + (l & 15)))*512u;
      #pragma unroll
      for(int kk = 0; kk < 8; kk++){
        bf16x8 av = *(const bf16x8*)(smem + ((rowX + (uint32_t)(kk*64) + koff) ^ sw));
        #pragma unroll
        for(int ni = 0; ni < 3; ni++){
          uint32_t rowW = ((uint32_t)(ni*16 + (l & 15)))*512u;
          bf16x8 bv = *(const bf16x8*)(smem + W2_OFF + ((rowW + (uint32_t)(kk*64) + koff) ^ sw));
          acc2[ni] = __builtin_amdgcn_mfma_f32_16x16x32_bf16(av, bv, acc2[ni], 0, 0, 0);
        }
      }
    }
    {
      float* ml = (float*)(smem + MASK_OFF);
      #pragma unroll
      for(int ni = 0; ni < 3; ni++){
        int co2 = ni*16 + (l & 15);
        float bb2 = b2[co2 < 36 ? co2 : 35];
        #pragma unroll
        for(int j = 0; j < 4; j++){
          int px = 16*w + ((l >> 4) << 2) + j;
          ml[px*48 + co2] = acc2[ni][j] + bb2;
        }
      }
    }
    bar_lds();

    // softmax(2x18) + unfold-merge, 4 threads per pixel (128 px per pass)
    {
      int px = tid >> 2;
      int hh = (tid >> 1) & 1;
      int c  = tid & 1;
      const float* ml = (const float*)(smem + MASK_OFF) + px*48 + hh*18;
      float mx = ml[0];
      #pragma unroll
      for(int k = 1; k < 18; k++) mx = fmaxf(mx, ml[k]);
      float e[18]; float sum = 0.f;
      #pragma unroll
      for(int k = 0; k < 18; k++){ e[k] = __expf(ml[k] - mx); sum += e[k]; }
      float inv = 1.f / sum;
      int p = p0 + pass*128 + px;
      int y = p / W_, x = p - y*W_;
      const float* fi = init_flow + (size_t)(b*4 + 2*hh + c)*NPIX;
      const float* ff = flow_fix  + (size_t)(b*4 + 2*hh + c)*NPIX;
      float o = 0.f;
      #pragma unroll
      for(int s = 0; s < 9; s++){
        int yy = y + (s/3) - 1, xx = x + (s%3) - 1;
        if(yy >= 0 && yy < H_ && xx >= 0 && xx < W_){
          int idx = yy*W_ + xx;
          o += e[s]*fi[idx] + e[9+s]*ff[idx];
        }
      }
      out[(size_t)((b + 2*hh)*2 + c)*NPIX + y*W_ + x] = o * inv;
    }
  }
}

// ---------------- launcher ----------------
extern "C" void kernel_launch(void* const* d_in, const int* in_sizes, int n_in,
                              void* d_out, int out_size, void* d_ws, size_t ws_size,
                              hipStream_t stream) {
  const float* feature   = (const float*)d_in[0];
  const float* init_flow = (const float*)d_in[1];
  const float* flow_fix  = (const float*)d_in[2];
  const float* w1        = (const float*)d_in[3];
  const float* b1        = (const float*)d_in[4];
  const float* prelu_w   = (const float*)d_in[5];
  const float* w2        = (const float*)d_in[6];
  const float* b2        = (const float*)d_in[7];
  float* out = (float*)d_out;
  uint8_t* ws = (uint8_t*)d_ws;

  if(ws_size < WS_NEEDED) return;  // insufficient workspace -> fail visibly

  prep_x<<<64*2*HP_, 256, 0, stream>>>(feature, ws);
  prep_f<<<2*HP_,    256, 0, stream>>>(init_flow, flow_fix, ws);
  prep_w<<<4736,     256, 0, stream>>>(w1, ws);
  mega<<<896, 512, 0, stream>>>(ws, w2, b1, prelu_w, b2, init_flow, flow_fix, out);
}

// Round 7
// 1717.511 us; speedup vs baseline: 1.1493x; 1.1493x over previous
//
#include <hip/hip_runtime.h>
#include <stdint.h>
#include <stddef.h>

typedef short bf16x8 __attribute__((ext_vector_type(8)));
typedef float f32x4  __attribute__((ext_vector_type(4)));
typedef unsigned short ushort_t;

#define H_ 256
#define W_ 448
#define HP_ 258
#define WP_ 450
#define NPIX (H_*W_)
#define PPLANE (HP_*WP_)

// ---------------- workspace layout (bytes) ----------------
#define XPAD_OFF 0ull
#define XPAD_CB_STRIDE ((size_t)2*PPLANE*16)      // 3,715,200 per ci-block of 8
#define XPAD_CB_STRIDE32 (3715200u)
#define XPAD_SIZE ((size_t)64*XPAD_CB_STRIDE)     // 237,772,800
#define FPAD_OFF (XPAD_OFF + XPAD_SIZE)
#define FPAD_SIZE ((size_t)2*PPLANE*16)           // 3,715,200
#define WT_OFF   (FPAD_OFF + FPAD_SIZE)
#define WT_SIZE  ((size_t)256*9*512*2)            // 2,359,296
#define WTF_OFF  (WT_OFF + WT_SIZE)
#define WTF_SIZE ((size_t)256*128*2)              // 65,536
#define WT2_OFF  (WTF_OFF + WTF_SIZE)
#define WT2_SIZE ((size_t)48*256*2)               // 24,576
#define WS_NEEDED (WT2_OFF + WT2_SIZE)

__device__ __forceinline__ ushort_t bf16r(float f){
  union { float f; uint32_t u; } c; c.f = f;
  uint32_t u = c.u;
  return (ushort_t)((u + 0x7FFFu + ((u >> 16) & 1u)) >> 16);
}

// ---------------- prep: features -> padded NHWC-blocked bf16 ----------------
__global__ void prep_x(const float* __restrict__ feat, uint8_t* __restrict__ ws){
  int blk = blockIdx.x;
  int yp = blk % HP_;
  int t  = blk / HP_;
  int b  = t & 1;
  int cb = t >> 1;
  uint8_t* dst = ws + XPAD_OFF + (size_t)(cb*2 + b)*((size_t)PPLANE*16) + (size_t)yp*WP_*16;
  bool inrow = (yp >= 1 && yp <= H_);
  const float* src0 = feat + ((size_t)b*512 + (size_t)cb*8)*((size_t)H_*W_) + (size_t)(yp-1)*W_;
  for(int xp = threadIdx.x; xp < WP_; xp += blockDim.x){
    union { ushort_t u[8]; uint4 q; } v;
    if(inrow && xp >= 1 && xp <= W_){
      int x = xp - 1;
      #pragma unroll
      for(int r = 0; r < 8; r++) v.u[r] = bf16r(src0[(size_t)r*H_*W_ + x]);
    } else {
      v.q = make_uint4(0,0,0,0);
    }
    *(uint4*)(dst + (size_t)xp*16) = v.q;
  }
}

// ---------------- prep: flows -> padded NHWC bf16 (8 ch records) ----------------
__global__ void prep_f(const float* __restrict__ init_flow, const float* __restrict__ flow_fix,
                       uint8_t* __restrict__ ws){
  int blk = blockIdx.x;
  int yp = blk % HP_;
  int b  = blk / HP_;
  uint8_t* dst = ws + FPAD_OFF + ((size_t)b*PPLANE + (size_t)yp*WP_)*16;
  for(int xp = threadIdx.x; xp < WP_; xp += blockDim.x){
    union { ushort_t u[8]; uint4 q; } v;
    if(yp >= 1 && yp <= H_ && xp >= 1 && xp <= W_){
      int y = yp - 1, x = xp - 1;
      #pragma unroll
      for(int r = 0; r < 4; r++) v.u[r]   = bf16r(init_flow[(((size_t)b*4 + r)*H_ + y)*W_ + x]);
      #pragma unroll
      for(int r = 0; r < 4; r++) v.u[4+r] = bf16r(flow_fix [(((size_t)b*4 + r)*H_ + y)*W_ + x]);
    } else {
      v.q = make_uint4(0,0,0,0);
    }
    *(uint4*)(dst + (size_t)xp*16) = v.q;
  }
}

// ---------------- prep: weights -> bf16, K-contiguous layouts ----------------
__global__ void prep_w(const float* __restrict__ w1, const float* __restrict__ w2,
                       uint8_t* __restrict__ ws){
  int idx = blockIdx.x*256 + threadIdx.x;
  ushort_t* wt  = (ushort_t*)(ws + WT_OFF);
  ushort_t* wtf = (ushort_t*)(ws + WTF_OFF);
  ushort_t* wt2 = (ushort_t*)(ws + WT2_OFF);
  if(idx < 256*9*512){
    int co  = idx / (9*512);
    int rem = idx % (9*512);
    int s   = rem / 512;
    int ci  = rem % 512;
    float v = w1[((size_t)co*520 + 8 + ci)*9 + s];
    wt[((size_t)co*9 + s)*512 + ci] = bf16r(v);
  } else if(idx < 256*9*512 + 256*128){
    int i2 = idx - 256*9*512;
    int co = i2 >> 7;
    int k  = i2 & 127;
    float v = 0.f;
    if(k < 64){ int s = k >> 3, c = k & 7; v = w1[((size_t)co*520 + c)*9 + s]; }
    else if(k < 72){ int c = k - 64;       v = w1[((size_t)co*520 + c)*9 + 8]; }
    wtf[co*128 + k] = bf16r(v);
  } else {
    int i3 = idx - 256*9*512 - 256*128;
    if(i3 < 48*256){
      int co2 = i3 >> 8, ci = i3 & 255;
      float v = (co2 < 36) ? w2[co2*256 + ci] : 0.f;
      wt2[co2*256 + ci] = bf16r(v);
    }
  }
}

// ---------------- fused conv3x3 + PReLU + conv1x1 + softmax + merge ----------------
// BM=128 px, BN=256 co, BK=64. 4 waves (2M x 2N), wave tile 64x128, acc[4][8].
// LDS 64KB -> 2 blocks/CU (independent barrier domains overlap LDS/MFMA, m114).
// A: 2x16K gload_lds double-buffer (2 tiles ahead). B: 32K single-buffer,
// reg-staged prefetch (T14): 8 dwordx4 -> regs before compute, ds_write after bar.
#define A0OFF 0u
#define A1OFF 16384u
#define BOFF  32768u
#define SMEM_TOTAL 65536

__device__ __forceinline__ void gload16(const uint8_t* g, uint8_t* l){
  __builtin_amdgcn_global_load_lds((const __attribute__((address_space(1))) uint32_t*)g,
                                   (__attribute__((address_space(3))) uint32_t*)l, 16, 0, 0);
}

__launch_bounds__(256, 2)
__global__ void mega(const uint8_t* __restrict__ ws,
                     const float* __restrict__ b1, const float* __restrict__ pw,
                     const float* __restrict__ b2,
                     const float* __restrict__ init_flow, const float* __restrict__ flow_fix,
                     float* __restrict__ out){
  __shared__ uint8_t smem[SMEM_TOTAL];
  const int tid = threadIdx.x;
  const int l   = tid & 63;
  const int w   = tid >> 6;                 // 0..3
  // T1: XCD-aware bijective swizzle (1792 = 8 * 224)
  const int blk0 = blockIdx.x;
  const int blk  = (blk0 & 7)*224 + (blk0 >> 3);
  const int b   = blk / 896;
  const int p0  = (blk % 896) * 128;

  // --- per-lane staging precompute (inverse-swizzled source addressing) ---
  uint32_t aoff[4], foff72[4]; uint32_t cb0m = 0;
  #pragma unroll
  for(int q = 0; q < 4; q++){
    uint32_t P = (uint32_t)(q*4096 + tid*16);
    uint32_t L = P ^ (((P >> 7) & 7u) << 4);
    int m  = (int)(L >> 7);           // 0..127 pixel row
    int cb = (int)((L >> 4) & 7u);    // ci-block within row
    int p  = p0 + m;
    int y  = p / W_, x = p - y*W_;
    int pixoff = (y + 1)*WP_ + (x + 1);
    aoff[q] = (uint32_t)cb*XPAD_CB_STRIDE32 + (uint32_t)(b*(PPLANE*16)) + (uint32_t)(pixoff*16);
    int dy = cb/3, dx = cb - dy*3;
    foff72[q] = (uint32_t)((b*PPLANE + pixoff + (dy-1)*WP_ + (dx-1))*16);
    if(cb == 0) cb0m |= (1u << q);
  }
  uint32_t boff[8];
  #pragma unroll
  for(int c = 0; c < 8; c++){
    uint32_t P = (uint32_t)(c*4096 + tid*16);
    uint32_t L = P ^ (((P >> 7) & 7u) << 4);
    uint32_t co = L >> 7, cib = L & 127u;
    boff[c] = co*9216u + cib;
  }

  const uint8_t* xpad = ws + XPAD_OFF;
  const uint8_t* fpad = ws + FPAD_OFF;
  const uint8_t* wt   = ws + WT_OFF;
  const uint8_t* wtf  = ws + WTF_OFF;

  // fragment-read per-lane constants
  const int wave_m = w >> 1, wave_n = w & 1;
  const uint32_t koff = ((uint32_t)(l >> 4))*16u;
  const uint32_t sw   = ((uint32_t)(l & 7)) << 4;
  const uint32_t rowA = ((uint32_t)(wave_m*64  + (l & 15)))*128u;
  const uint32_t rowB = ((uint32_t)(wave_n*128 + (l & 15)))*128u;

  const f32x4 zero4 = {0.f, 0.f, 0.f, 0.f};
  f32x4 acc[4][8];
  #pragma unroll
  for(int i = 0; i < 4; i++)
    #pragma unroll
    for(int j = 0; j < 8; j++) acc[i][j] = zero4;

  auto issueA = [&](int tn, uint32_t bufbase){
    uint8_t* dst = smem + bufbase + (uint32_t)(tid*16);
    if(tn < 72){
      int s = tn >> 3, kk = tn & 7;
      int dy = s/3, dx = s - dy*3;
      uint32_t stepA = (uint32_t)(kk*8)*XPAD_CB_STRIDE32 + (uint32_t)(((dy-1)*WP_ + (dx-1))*16);
      #pragma unroll
      for(int q = 0; q < 4; q++) gload16(xpad + (aoff[q] + stepA), dst + q*4096);
    } else if(tn == 72){
      #pragma unroll
      for(int q = 0; q < 4; q++) gload16(fpad + foff72[q], dst + q*4096);
    } else {
      #pragma unroll
      for(int q = 0; q < 4; q++){
        uint32_t o = ((cb0m >> q) & 1u) ? (foff72[q] + (uint32_t)(2*(WP_+1)*16)) : 0u;
        gload16(fpad + o, dst + q*4096);   // fpad record 0 is a border pixel: zeros
      }
    }
  };
  uint4 br[8];
  auto loadBregs = [&](int tn){
    if(tn < 72){
      uint32_t stepB = (uint32_t)((tn >> 3)*1024 + (tn & 7)*128);
      #pragma unroll
      for(int c = 0; c < 8; c++) br[c] = *(const uint4*)(wt + (boff[c] + stepB));
    } else {
      uint32_t add = (tn == 72) ? 0u : 128u;
      #pragma unroll
      for(int c = 0; c < 8; c++){
        uint32_t P = (uint32_t)(c*4096 + tid*16);
        uint32_t L = P ^ (((P >> 7) & 7u) << 4);
        br[c] = *(const uint4*)(wtf + ((L >> 7)*256u + (L & 127u) + add));
      }
    }
  };
  auto writeB = [&](){
    #pragma unroll
    for(int c = 0; c < 8; c++)
      *(uint4*)(smem + BOFF + (uint32_t)(c*4096 + tid*16)) = br[c];
  };

  // prologue: A(0)->buf0, A(1)->buf1, B(0)->regs; drain; write B(0); barrier
  issueA(0, A0OFF);
  issueA(1, A1OFF);
  loadBregs(0);
  asm volatile("s_waitcnt vmcnt(0)" ::: "memory");
  writeB();
  asm volatile("s_waitcnt lgkmcnt(0)" ::: "memory");
  __builtin_amdgcn_s_barrier();
  asm volatile("" ::: "memory");

  for(int t = 0; t < 74; t++){
    if(t < 73) loadBregs(t + 1);                       // B(t+1) -> regs (in flight over compute)
    const uint8_t* A = smem + (uint32_t)((t & 1) << 14);
    #pragma unroll
    for(int kc = 0; kc < 2; kc++){
      bf16x8 av[4];
      #pragma unroll
      for(int mi = 0; mi < 4; mi++)
        av[mi] = *(const bf16x8*)(A + ((rowA + (uint32_t)(mi*2048 + kc*64) + koff) ^ sw));
      #pragma unroll
      for(int nq = 0; nq < 2; nq++){
        bf16x8 bv[4];
        #pragma unroll
        for(int nj = 0; nj < 4; nj++)
          bv[nj] = *(const bf16x8*)(smem + BOFF + ((rowB + (uint32_t)((nq*4+nj)*2048 + kc*64) + koff) ^ sw));
        __builtin_amdgcn_s_setprio(1);
        #pragma unroll
        for(int nj = 0; nj < 4; nj++)
          #pragma unroll
          for(int mi = 0; mi < 4; mi++)
            acc[mi][nq*4+nj] = __builtin_amdgcn_mfma_f32_16x16x32_bf16(av[mi], bv[nj], acc[mi][nq*4+nj], 0, 0, 0);
        __builtin_amdgcn_s_setprio(0);
      }
    }
    asm volatile("s_waitcnt vmcnt(0)" ::: "memory");   // A(t+1) (1 iter old) + B(t+1) regs landed
    __builtin_amdgcn_s_barrier();                      // all reads of Bbuf & A(t) done
    asm volatile("" ::: "memory");
    if(t < 73) writeB();                               // B(t+1) -> LDS
    if(t < 72) issueA(t + 2, (uint32_t)((t & 1) << 14)); // A(t+2) into freed buf
    asm volatile("s_waitcnt lgkmcnt(0)" ::: "memory");
    __builtin_amdgcn_s_barrier();
    asm volatile("" ::: "memory");
  }

  // --- epilogue (fused): PReLU -> x [128px][256co] bf16 over whole LDS ---
  #pragma unroll
  for(int ni = 0; ni < 8; ni++){
    int co = wave_n*128 + ni*16 + (l & 15);
    float bb = b1[co];
    float pp = pw[co];
    #pragma unroll
    for(int mi = 0; mi < 4; mi++){
      #pragma unroll
      for(int j = 0; j < 4; j++){
        float v = acc[mi][ni][j] + bb;
        v = (v < 0.f) ? v*pp : v;
        int px = wave_m*64 + mi*16 + ((l >> 4) << 2) + j;
        uint32_t phys = ((uint32_t)(px*512 + co*2)) ^ (((uint32_t)(px & 7)) << 4);
        *(ushort_t*)(smem + phys) = bf16r(v);
      }
    }
  }
  asm volatile("s_waitcnt lgkmcnt(0)" ::: "memory");
  __builtin_amdgcn_s_barrier();
  asm volatile("" ::: "memory");

  // --- mask GEMM: wave w -> px rows [32w, 32w+32), N=48 (36 valid), K=256.
  //     A from LDS x; B (W2 bf16) direct from global (L2-hot). ---
  const ushort_t* wt2g = (const ushort_t*)(ws + WT2_OFF);
  f32x4 acc2[2][3];
  #pragma unroll
  for(int i = 0; i < 2; i++)
    #pragma unroll
    for(int j = 0; j < 3; j++) acc2[i][j] = zero4;
  #pragma unroll
  for(int kk = 0; kk < 8; kk++){
    bf16x8 bv3[3];
    #pragma unroll
    for(int cob = 0; cob < 3; cob++){
      int co2 = cob*16 + (l & 15);
      int co2s = (co2 < 36) ? co2 : 0;
      bv3[cob] = *(const bf16x8*)(wt2g + co2s*256 + kk*32 + (l >> 4)*8);
    }
    #pragma unroll
    for(int pxb = 0; pxb < 2; pxb++){
      uint32_t rowX = ((uint32_t)(32*w + pxb*16 + (l & 15)))*512u;
      bf16x8 av = *(const bf16x8*)(smem + ((rowX + (uint32_t)(kk*64) + koff) ^ sw));
      #pragma unroll
      for(int cob = 0; cob < 3; cob++)
        acc2[pxb][cob] = __builtin_amdgcn_mfma_f32_16x16x32_bf16(av, bv3[cob], acc2[pxb][cob], 0, 0, 0);
    }
  }
  asm volatile("s_waitcnt lgkmcnt(0)" ::: "memory");
  __builtin_amdgcn_s_barrier();     // all x reads done before mask overwrites LDS
  asm volatile("" ::: "memory");
  {
    float* ml = (float*)smem;       // mask f32 [128][48] = 24 KB
    #pragma unroll
    for(int pxb = 0; pxb < 2; pxb++){
      #pragma unroll
      for(int cob = 0; cob < 3; cob++){
        int co2 = cob*16 + (l & 15);
        if(co2 < 36){
          float bb2 = b2[co2];
          #pragma unroll
          for(int j = 0; j < 4; j++){
            int px = 32*w + pxb*16 + ((l >> 4) << 2) + j;
            ml[px*48 + co2] = acc2[pxb][cob][j] + bb2;
          }
        }
      }
    }
  }
  asm volatile("s_waitcnt lgkmcnt(0)" ::: "memory");
  __builtin_amdgcn_s_barrier();
  asm volatile("" ::: "memory");

  // --- softmax(2x18) + unfold-merge: 512 tasks on 256 threads ---
  #pragma unroll
  for(int it = 0; it < 2; it++){
    int task = tid + it*256;
    int px = task >> 2;
    int hh = (task >> 1) & 1;
    int c  = task & 1;
    const float* ml = (const float*)smem + px*48 + hh*18;
    float mx = ml[0];
    #pragma unroll
    for(int k = 1; k < 18; k++) mx = fmaxf(mx, ml[k]);
    float e[18]; float sum = 0.f;
    #pragma unroll
    for(int k = 0; k < 18; k++){ e[k] = __expf(ml[k] - mx); sum += e[k]; }
    float inv = 1.f / sum;
    int p = p0 + px;
    int y = p / W_, x = p - y*W_;
    const float* fi = init_flow + (size_t)(b*4 + 2*hh + c)*NPIX;
    const float* ff = flow_fix  + (size_t)(b*4 + 2*hh + c)*NPIX;
    float o = 0.f;
    #pragma unroll
    for(int s = 0; s < 9; s++){
      int yy = y + (s/3) - 1, xx = x + (s%3) - 1;
      if(yy >= 0 && yy < H_ && xx >= 0 && xx < W_){
        int idx = yy*W_ + xx;
        o += e[s]*fi[idx] + e[9+s]*ff[idx];
      }
    }
    out[(size_t)((b + 2*hh)*2 + c)*NPIX + y*W_ + x] = o * inv;
  }
}

// ---------------- launcher ----------------
extern "C" void kernel_launch(void* const* d_in, const int* in_sizes, int n_in,
                              void* d_out, int out_size, void* d_ws, size_t ws_size,
                              hipStream_t stream) {
  const float* feature   = (const float*)d_in[0];
  const float* init_flow = (const float*)d_in[1];
  const float* flow_fix  = (const float*)d_in[2];
  const float* w1        = (const float*)d_in[3];
  const float* b1        = (const float*)d_in[4];
  const float* prelu_w   = (const float*)d_in[5];
  const float* w2        = (const float*)d_in[6];
  const float* b2        = (const float*)d_in[7];
  float* out = (float*)d_out;
  uint8_t* ws = (uint8_t*)d_ws;

  if(ws_size < WS_NEEDED) return;  // insufficient workspace -> fail visibly

  prep_x<<<64*2*HP_, 256, 0, stream>>>(feature, ws);
  prep_f<<<2*HP_,    256, 0, stream>>>(init_flow, flow_fix, ws);
  prep_w<<<4784,     256, 0, stream>>>(w1, w2, ws);
  mega<<<1792, 256, 0, stream>>>(ws, b1, prelu_w, b2, init_flow, flow_fix, out);
}

// Round 8
// 1519.273 us; speedup vs baseline: 1.2992x; 1.1305x over previous
//
#include <hip/hip_runtime.h>
#include <stdint.h>
#include <stddef.h>

typedef short bf16x8 __attribute__((ext_vector_type(8)));
typedef float f32x4  __attribute__((ext_vector_type(4)));
typedef unsigned short ushort_t;

#define H_ 256
#define W_ 448
#define HP_ 258
#define WP_ 450
#define NPIX (H_*W_)
#define PPLANE (HP_*WP_)

// ---------------- workspace layout (bytes) ----------------
#define XPAD_OFF 0ull
#define XPAD_CB_STRIDE ((size_t)2*PPLANE*16)      // 3,715,200 per ci-block of 8
#define XPAD_CB_STRIDE32 (3715200u)
#define XPAD_SIZE ((size_t)64*XPAD_CB_STRIDE)     // 237,772,800
#define FPAD_OFF (XPAD_OFF + XPAD_SIZE)
#define FPAD_SIZE ((size_t)2*PPLANE*16)           // 3,715,200
#define WT_OFF   (FPAD_OFF + FPAD_SIZE)
#define WT_SIZE  ((size_t)256*9*512*2)            // 2,359,296
#define WTF_OFF  (WT_OFF + WT_SIZE)
#define WTF_SIZE ((size_t)256*128*2)              // 65,536
#define WS_NEEDED (WTF_OFF + WTF_SIZE)

__device__ __forceinline__ ushort_t bf16r(float f){
  union { float f; uint32_t u; } c; c.f = f;
  uint32_t u = c.u;
  return (ushort_t)((u + 0x7FFFu + ((u >> 16) & 1u)) >> 16);
}

// ---------------- prep: features -> padded NHWC-blocked bf16 ----------------
__global__ void prep_x(const float* __restrict__ feat, uint8_t* __restrict__ ws){
  int blk = blockIdx.x;
  int yp = blk % HP_;
  int t  = blk / HP_;
  int b  = t & 1;
  int cb = t >> 1;
  uint8_t* dst = ws + XPAD_OFF + (size_t)(cb*2 + b)*((size_t)PPLANE*16) + (size_t)yp*WP_*16;
  bool inrow = (yp >= 1 && yp <= H_);
  const float* src0 = feat + ((size_t)b*512 + (size_t)cb*8)*((size_t)H_*W_) + (size_t)(yp-1)*W_;
  for(int xp = threadIdx.x; xp < WP_; xp += blockDim.x){
    union { ushort_t u[8]; uint4 q; } v;
    if(inrow && xp >= 1 && xp <= W_){
      int x = xp - 1;
      #pragma unroll
      for(int r = 0; r < 8; r++) v.u[r] = bf16r(src0[(size_t)r*H_*W_ + x]);
    } else {
      v.q = make_uint4(0,0,0,0);
    }
    *(uint4*)(dst + (size_t)xp*16) = v.q;
  }
}

// ---------------- prep: flows -> padded NHWC bf16 (8 ch records) ----------------
__global__ void prep_f(const float* __restrict__ init_flow, const float* __restrict__ flow_fix,
                       uint8_t* __restrict__ ws){
  int blk = blockIdx.x;
  int yp = blk % HP_;
  int b  = blk / HP_;
  uint8_t* dst = ws + FPAD_OFF + ((size_t)b*PPLANE + (size_t)yp*WP_)*16;
  for(int xp = threadIdx.x; xp < WP_; xp += blockDim.x){
    union { ushort_t u[8]; uint4 q; } v;
    if(yp >= 1 && yp <= H_ && xp >= 1 && xp <= W_){
      int y = yp - 1, x = xp - 1;
      #pragma unroll
      for(int r = 0; r < 4; r++) v.u[r]   = bf16r(init_flow[(((size_t)b*4 + r)*H_ + y)*W_ + x]);
      #pragma unroll
      for(int r = 0; r < 4; r++) v.u[4+r] = bf16r(flow_fix [(((size_t)b*4 + r)*H_ + y)*W_ + x]);
    } else {
      v.q = make_uint4(0,0,0,0);
    }
    *(uint4*)(dst + (size_t)xp*16) = v.q;
  }
}

// ---------------- prep: weights -> bf16, K-contiguous layouts ----------------
__global__ void prep_w(const float* __restrict__ w1, uint8_t* __restrict__ ws){
  int idx = blockIdx.x*256 + threadIdx.x;
  ushort_t* wt  = (ushort_t*)(ws + WT_OFF);
  ushort_t* wtf = (ushort_t*)(ws + WTF_OFF);
  if(idx < 256*9*512){
    int co  = idx / (9*512);
    int rem = idx % (9*512);
    int s   = rem / 512;
    int ci  = rem % 512;
    float v = w1[((size_t)co*520 + 8 + ci)*9 + s];
    wt[((size_t)co*9 + s)*512 + ci] = bf16r(v);
  } else {
    int i2 = idx - 256*9*512;
    if(i2 < 256*128){
      int co = i2 >> 7;
      int k  = i2 & 127;
      float v = 0.f;
      if(k < 64){ int s = k >> 3, c = k & 7; v = w1[((size_t)co*520 + c)*9 + s]; }
      else if(k < 72){ int c = k - 64;       v = w1[((size_t)co*520 + c)*9 + 8]; }
      wtf[co*128 + k] = bf16r(v);
    }
  }
}

// ---------------- fused conv3x3 + PReLU + conv1x1 + softmax + merge ----------------
// HALO-REUSE: taps grouped by row-offset dy. Per unit u=(dy,c8 of 64ch): stage ONE
// 260-record strip (tile 256px + 1px halo, linear in padded memory); 3 column-taps
// (dxs=0..2) are K=64 steps reading the strip at +dxs record offset. A bytes/block
// 2.37MB -> 0.86MB; A-prefetch cover 3 steps. B path identical to R4 (per-step 32K).
// Steps: 24 units x 3 + 2 flow = 74. BM=256,BN=256,BK=64, 8 waves, wave tile 128x64.
// LDS: A dbuf 2x33280 @0; B dbuf 2x32768 @66560; total 132096. Epilogue reuses.
#define ABUF_SZ 33280u
#define BBASE   66560u
#define MASK_OFF 65536
#define W2_OFF   90112
#define SMEM_TOTAL 132096

__device__ __forceinline__ void gload16(const uint8_t* g, uint8_t* l){
  __builtin_amdgcn_global_load_lds((const __attribute__((address_space(1))) uint32_t*)g,
                                   (__attribute__((address_space(3))) uint32_t*)l, 16, 0, 0);
}
__device__ __forceinline__ void bar(){
  asm volatile("" ::: "memory");
  __builtin_amdgcn_s_barrier();
  asm volatile("" ::: "memory");
}
__device__ __forceinline__ void bar_lds(){
  asm volatile("s_waitcnt lgkmcnt(0)" ::: "memory");
  __builtin_amdgcn_s_barrier();
  asm volatile("" ::: "memory");
}

__launch_bounds__(512, 2)
__global__ void mega(const uint8_t* __restrict__ ws, const float* __restrict__ w2,
                     const float* __restrict__ b1, const float* __restrict__ pw,
                     const float* __restrict__ b2,
                     const float* __restrict__ init_flow, const float* __restrict__ flow_fix,
                     float* __restrict__ out){
  __shared__ uint8_t smem[SMEM_TOTAL];
  const int tid = threadIdx.x;
  const int l   = tid & 63;
  const int w   = tid >> 6;
  // T1: XCD-aware bijective swizzle (896 = 8 * 112)
  const int blk0 = blockIdx.x;
  const int blk  = (blk0 & 7)*112 + (blk0 >> 3);
  const int b   = blk / 448;
  const int p0  = (blk % 448) * 256;
  const int y0  = p0 / W_;
  const int x0  = p0 - y0*W_;
  const int xcross = W_ - x0;          // >=256 means "no crossing" (m<=255)

  const uint8_t* xpad = ws + XPAD_OFF;
  const uint8_t* fpad = ws + FPAD_OFF;
  const uint8_t* wt   = ws + WT_OFF;
  const uint8_t* wtf  = ws + WTF_OFF;

  // fragment-read per-lane constants
  const int wave_m = w >> 2, wave_n = w & 3;
  const uint32_t koff = ((uint32_t)(l >> 4))*16u;
  const uint32_t swB  = ((uint32_t)(l & 7)) << 4;
  const uint32_t rowA = ((uint32_t)(wave_m*128 + (l & 15)))*128u;   // flow tiles
  const uint32_t rowB = ((uint32_t)(wave_n*64  + (l & 15)))*128u;

  // strip row index per mi (includes +2 row-crossing adjust)
  int rpX[8];
  #pragma unroll
  for(int mi = 0; mi < 8; mi++){
    int m = wave_m*128 + mi*16 + (l & 15);
    rpX[mi] = m + ((m >= xcross) ? 2 : 0);
  }

  // staging source offsets (pure functions of (chunk,tid)); D -> unswizzle
  uint32_t soffA[4], soffAp = 0;
  #pragma unroll
  for(int q = 0; q < 4; q++){
    uint32_t D = (uint32_t)(q*8192 + tid*16);
    uint32_t slot = ((D >> 4) & 7u) ^ ((D >> 7) & 7u);
    soffA[q] = slot*XPAD_CB_STRIDE32 + (D >> 7)*16u;
  }
  if(tid < 32){
    uint32_t D = 32768u + (uint32_t)(tid*16);
    uint32_t slot = ((D >> 4) & 7u) ^ ((D >> 7) & 7u);
    soffAp = slot*XPAD_CB_STRIDE32 + (D >> 7)*16u;
  }
  uint32_t boff[4], bfl[4];
  #pragma unroll
  for(int r = 0; r < 4; r++){
    uint32_t P = (uint32_t)(r*8192 + tid*16);
    uint32_t L = P ^ (((P >> 7) & 7u) << 4);
    uint32_t co = L >> 7, cib = L & 127u;
    boff[r] = co*9216u + cib;
    bfl[r]  = co*256u + cib;
  }

  const f32x4 zero4 = {0.f, 0.f, 0.f, 0.f};
  f32x4 acc[8][4];
  #pragma unroll
  for(int i = 0; i < 8; i++)
    #pragma unroll
    for(int j = 0; j < 4; j++) acc[i][j] = zero4;

  // A-unit source base for unit u1 (0..23): strip j=0 record = (y0+dy)*WP_ + x0
  auto Abase = [&](int u1) -> uint32_t {
    int dy = u1 >> 3, c8 = u1 & 7;
    return (uint32_t)(c8*8)*XPAD_CB_STRIDE32 + (uint32_t)(b*(PPLANE*16))
         + (uint32_t)(((y0 + dy)*WP_ + x0)*16);
  };
  auto stA_main = [&](uint32_t base, int buf){
    uint8_t* dst = smem + (uint32_t)buf*ABUF_SZ + (uint32_t)(tid*16);
    #pragma unroll
    for(int q = 0; q < 4; q++) gload16(xpad + (base + soffA[q]), dst + q*8192);
  };
  auto stA_part = [&](uint32_t base, int buf){
    if(tid < 32) gload16(xpad + (base + soffAp),
                         smem + (uint32_t)buf*ABUF_SZ + 32768u + (uint32_t)(tid*16));
  };
  auto stA_flow = [&](int which, int buf){   // which: 0 -> taps 0..7, 1 -> tap 8
    uint8_t* dst = smem + (uint32_t)buf*ABUF_SZ + (uint32_t)(tid*16);
    #pragma unroll
    for(int q = 0; q < 4; q++){
      uint32_t P = (uint32_t)(q*8192 + tid*16);
      uint32_t L = P ^ (((P >> 7) & 7u) << 4);
      int m  = (int)(L >> 7);
      int cb = (int)((L >> 4) & 7u);
      int p  = p0 + m;
      int y  = p / W_, x = p - y*W_;
      int pixoff = (y + 1)*WP_ + (x + 1);
      uint32_t off;
      if(which == 0){
        int dy = cb/3, dx = cb - dy*3;
        off = (uint32_t)((b*PPLANE + pixoff + (dy-1)*WP_ + (dx-1))*16);
      } else {
        off = (cb == 0) ? (uint32_t)((b*PPLANE + pixoff + WP_ + 1)*16) : 0u;
      }
      gload16(fpad + off, dst + q*8192);
    }
  };
  auto stB = [&](int us, int ds){            // B for main step (us, ds)
    uint32_t s1 = (uint32_t)((us >> 3)*3 + ds);
    uint32_t stepB = s1*1024u + (uint32_t)(us & 7)*128u;
    uint8_t* lb = smem + BBASE + (uint32_t)(((us + ds) & 1)*32768) + (uint32_t)(tid*16);
    #pragma unroll
    for(int r = 0; r < 4; r++) gload16(wt + (boff[r] + stepB), lb + r*8192);
  };
  auto stBf = [&](int add, int buf){         // flow B tiles
    uint8_t* lb = smem + BBASE + (uint32_t)(buf*32768) + (uint32_t)(tid*16);
    #pragma unroll
    for(int r = 0; r < 4; r++) gload16(wtf + (bfl[r] + (uint32_t)add), lb + r*8192);
  };

  auto COMPUTE_MAIN = [&](const uint8_t* Ab, const uint8_t* Bb, int dxs){
    #pragma unroll
    for(int kc = 0; kc < 2; kc++){
      const uint32_t inner = (uint32_t)(kc*64) + koff;
      bf16x8 av[8], bv[4];
      #pragma unroll
      for(int mi = 0; mi < 8; mi++){
        uint32_t Aidx = (uint32_t)(rpX[mi] + dxs);
        av[mi] = *(const bf16x8*)(Ab + ((Aidx << 7) + (inner ^ ((Aidx & 7u) << 4))));
      }
      #pragma unroll
      for(int ni = 0; ni < 4; ni++)
        bv[ni] = *(const bf16x8*)(Bb + (rowB + (uint32_t)(ni*2048) + (inner ^ swB)));
      __builtin_amdgcn_s_setprio(1);
      #pragma unroll
      for(int ni = 0; ni < 4; ni++)
        #pragma unroll
        for(int mi = 0; mi < 8; mi++)
          acc[mi][ni] = __builtin_amdgcn_mfma_f32_16x16x32_bf16(av[mi], bv[ni], acc[mi][ni], 0, 0, 0);
      __builtin_amdgcn_s_setprio(0);
    }
  };
  auto COMPUTE_FLOW = [&](const uint8_t* Ab, const uint8_t* Bb){
    #pragma unroll
    for(int kc = 0; kc < 2; kc++){
      const uint32_t inner = (uint32_t)(kc*64) + koff;
      bf16x8 av[8], bv[4];
      #pragma unroll
      for(int mi = 0; mi < 8; mi++)
        av[mi] = *(const bf16x8*)(Ab + ((rowA + (uint32_t)(mi*2048)) + (inner ^ swB)));
      #pragma unroll
      for(int ni = 0; ni < 4; ni++)
        bv[ni] = *(const bf16x8*)(Bb + (rowB + (uint32_t)(ni*2048) + (inner ^ swB)));
      __builtin_amdgcn_s_setprio(1);
      #pragma unroll
      for(int ni = 0; ni < 4; ni++)
        #pragma unroll
        for(int mi = 0; mi < 8; mi++)
          acc[mi][ni] = __builtin_amdgcn_mfma_f32_16x16x32_bf16(av[mi], bv[ni], acc[mi][ni], 0, 0, 0);
      __builtin_amdgcn_s_setprio(0);
    }
  };

  // prologue: A-unit0 -> buf0, B(step0) -> Bbuf0; full drain once
  {
    uint32_t base0 = Abase(0);
    stA_part(base0, 0);
    stB(0, 0);
    stA_main(base0, 0);
  }
  asm volatile("s_waitcnt vmcnt(0)" ::: "memory");
  bar();

  // main loop: 24 units x 3 dxs steps
  #pragma unroll 1
  for(int u = 0; u < 24; u++){
    const uint8_t* Ab = smem + (uint32_t)((u & 1))*ABUF_SZ;
    #pragma unroll
    for(int dxs = 0; dxs < 3; dxs++){
      if(dxs == 0){
        if(u < 23){
          uint32_t base1 = Abase(u + 1);
          stA_part(base1, (u + 1) & 1);      // issued FIRST (oldest of this step)
          stB(u, 1);
          stA_main(base1, (u + 1) & 1);
          if(w == 0) asm volatile("s_waitcnt vmcnt(9)" ::: "memory");
          else       asm volatile("s_waitcnt vmcnt(8)" ::: "memory");
        } else {                             // u == 23: stage flow tile 1 (no partial)
          stB(u, 1);
          stA_flow(0, 0);
          asm volatile("s_waitcnt vmcnt(8)" ::: "memory");
        }
      } else if(dxs == 1){
        stB(u, 2);
        asm volatile("s_waitcnt vmcnt(8)" ::: "memory");
      } else {
        if(u < 23) stB(u + 1, 0);
        else       stBf(0, 0);               // B for flow step 72 -> Bbuf0
        asm volatile("s_waitcnt vmcnt(4)" ::: "memory");
      }
      bar();
      COMPUTE_MAIN(Ab, smem + BBASE + (uint32_t)(((u + dxs) & 1)*32768), dxs);
      bar();
    }
  }
  // t = 72 (flow tile 1 in Abuf0 / Bbuf0)
  stBf(128, 1);
  stA_flow(1, 1);
  asm volatile("s_waitcnt vmcnt(8)" ::: "memory");
  bar();
  COMPUTE_FLOW(smem, smem + BBASE);
  bar();
  // t = 73 (flow tile 2 in Abuf1 / Bbuf1)
  asm volatile("s_waitcnt vmcnt(0)" ::: "memory");
  bar();
  COMPUTE_FLOW(smem + ABUF_SZ, smem + BBASE + 32768u);
  bar();

  // --- stage W2 (fp32 -> bf16) into LDS, rows of 512B, XOR-swizzled ---
  for(int e2 = tid; e2 < 48*256; e2 += 512){
    int row = e2 >> 8, k = e2 & 255;
    float f = (row < 36) ? w2[row*256 + k] : 0.f;
    uint32_t phys = ((uint32_t)(row*512 + k*2)) ^ (((uint32_t)(row & 7)) << 4);
    *(ushort_t*)(smem + W2_OFF + phys) = bf16r(f);
  }

  // --- epilogue: two passes of 128 pixels each ---
  #pragma unroll
  for(int pass = 0; pass < 2; pass++){
    if(pass) bar();   // pass-0 softmax/merge done before overwriting x-half & mask
    if(wave_m == pass){
      #pragma unroll
      for(int ni = 0; ni < 4; ni++){
        int co = wave_n*64 + ni*16 + (l & 15);
        float bb = b1[co];
        float pp = pw[co];
        #pragma unroll
        for(int mi = 0; mi < 8; mi++){
          #pragma unroll
          for(int j = 0; j < 4; j++){
            float v = acc[mi][ni][j] + bb;
            v = (v < 0.f) ? v*pp : v;
            int px = mi*16 + ((l >> 4) << 2) + j;     // 0..127 within the pass
            uint32_t phys = ((uint32_t)(px*512 + co*2)) ^ (((uint32_t)(px & 7)) << 4);
            *(ushort_t*)(smem + phys) = bf16r(v);
          }
        }
      }
    }
    bar_lds();   // x-half (and W2 on pass 0) visible to all

    // mask GEMM: wave w -> pixel rows [16w, 16w+16), N=48 (36 valid), K=256
    f32x4 acc2[3];
    #pragma unroll
    for(int ni = 0; ni < 3; ni++) acc2[ni] = zero4;
    {
      const uint32_t rowX = ((uint32_t)(16*w + (l & 15)))*512u;
      #pragma unroll
      for(int kk = 0; kk < 8; kk++){
        bf16x8 av = *(const bf16x8*)(smem + ((rowX + (uint32_t)(kk*64) + koff) ^ swB));
        #pragma unroll
        for(int ni = 0; ni < 3; ni++){
          uint32_t rowW = ((uint32_t)(ni*16 + (l & 15)))*512u;
          bf16x8 bv = *(const bf16x8*)(smem + W2_OFF + ((rowW + (uint32_t)(kk*64) + koff) ^ swB));
          acc2[ni] = __builtin_amdgcn_mfma_f32_16x16x32_bf16(av, bv, acc2[ni], 0, 0, 0);
        }
      }
    }
    {
      float* ml = (float*)(smem + MASK_OFF);
      #pragma unroll
      for(int ni = 0; ni < 3; ni++){
        int co2 = ni*16 + (l & 15);
        float bb2 = b2[co2 < 36 ? co2 : 35];
        #pragma unroll
        for(int j = 0; j < 4; j++){
          int px = 16*w + ((l >> 4) << 2) + j;
          ml[px*48 + co2] = acc2[ni][j] + bb2;
        }
      }
    }
    bar_lds();

    // softmax(2x18) + unfold-merge, 4 threads per pixel (128 px per pass)
    {
      int px = tid >> 2;
      int hh = (tid >> 1) & 1;
      int c  = tid & 1;
      const float* ml = (const float*)(smem + MASK_OFF) + px*48 + hh*18;
      float mx = ml[0];
      #pragma unroll
      for(int k = 1; k < 18; k++) mx = fmaxf(mx, ml[k]);
      float e[18]; float sum = 0.f;
      #pragma unroll
      for(int k = 0; k < 18; k++){ e[k] = __expf(ml[k] - mx); sum += e[k]; }
      float inv = 1.f / sum;
      int p = p0 + pass*128 + px;
      int y = p / W_, x = p - y*W_;
      const float* fi = init_flow + (size_t)(b*4 + 2*hh + c)*NPIX;
      const float* ff = flow_fix  + (size_t)(b*4 + 2*hh + c)*NPIX;
      float o = 0.f;
      #pragma unroll
      for(int s = 0; s < 9; s++){
        int yy = y + (s/3) - 1, xx = x + (s%3) - 1;
        if(yy >= 0 && yy < H_ && xx >= 0 && xx < W_){
          int idx = yy*W_ + xx;
          o += e[s]*fi[idx] + e[9+s]*ff[idx];
        }
      }
      out[(size_t)((b + 2*hh)*2 + c)*NPIX + y*W_ + x] = o * inv;
    }
  }
}

// ---------------- launcher ----------------
extern "C" void kernel_launch(void* const* d_in, const int* in_sizes, int n_in,
                              void* d_out, int out_size, void* d_ws, size_t ws_size,
                              hipStream_t stream) {
  const float* feature   = (const float*)d_in[0];
  const float* init_flow = (const float*)d_in[1];
  const float* flow_fix  = (const float*)d_in[2];
  const float* w1        = (const float*)d_in[3];
  const float* b1        = (const float*)d_in[4];
  const float* prelu_w   = (const float*)d_in[5];
  const float* w2        = (const float*)d_in[6];
  const float* b2        = (const float*)d_in[7];
  float* out = (float*)d_out;
  uint8_t* ws = (uint8_t*)d_ws;

  if(ws_size < WS_NEEDED) return;  // insufficient workspace -> fail visibly

  prep_x<<<64*2*HP_, 256, 0, stream>>>(feature, ws);
  prep_f<<<2*HP_,    256, 0, stream>>>(init_flow, flow_fix, ws);
  prep_w<<<4736,     256, 0, stream>>>(w1, ws);
  mega<<<896, 512, 0, stream>>>(ws, w2, b1, prelu_w, b2, init_flow, flow_fix, out);
}

// Round 9
// 673.279 us; speedup vs baseline: 2.9317x; 2.2565x over previous
//
#include <hip/hip_runtime.h>
#include <stdint.h>
#include <stddef.h>

typedef short bf16x8 __attribute__((ext_vector_type(8)));
typedef float f32x4  __attribute__((ext_vector_type(4)));
typedef unsigned short ushort_t;

#define H_ 256
#define W_ 448
#define HP_ 258
#define WP_ 450
#define NPIX (H_*W_)
#define PPLANE (HP_*WP_)

// ---------------- workspace layout (bytes) ----------------
#define XPAD_OFF 0ull
#define XPAD_CB_STRIDE ((size_t)2*PPLANE*16)      // 3,715,200 per ci-block of 8
#define XPAD_CB_STRIDE32 (3715200u)
#define XPAD_SIZE ((size_t)64*XPAD_CB_STRIDE)     // 237,772,800
#define FPAD_OFF (XPAD_OFF + XPAD_SIZE)
#define FPAD_SIZE ((size_t)2*PPLANE*16)           // 3,715,200
#define WT_OFF   (FPAD_OFF + FPAD_SIZE)
#define WT_SIZE  ((size_t)256*9*512*2)            // 2,359,296
#define WTF_OFF  (WT_OFF + WT_SIZE)
#define WTF_SIZE ((size_t)256*128*2)              // 65,536
#define WS_NEEDED (WTF_OFF + WTF_SIZE)

__device__ __forceinline__ ushort_t bf16r(float f){
  union { float f; uint32_t u; } c; c.f = f;
  uint32_t u = c.u;
  return (ushort_t)((u + 0x7FFFu + ((u >> 16) & 1u)) >> 16);
}

// ---------------- prep: features -> padded NHWC-blocked bf16 ----------------
__global__ void prep_x(const float* __restrict__ feat, uint8_t* __restrict__ ws){
  int blk = blockIdx.x;
  int yp = blk % HP_;
  int t  = blk / HP_;
  int b  = t & 1;
  int cb = t >> 1;
  uint8_t* dst = ws + XPAD_OFF + (size_t)(cb*2 + b)*((size_t)PPLANE*16) + (size_t)yp*WP_*16;
  bool inrow = (yp >= 1 && yp <= H_);
  const float* src0 = feat + ((size_t)b*512 + (size_t)cb*8)*((size_t)H_*W_) + (size_t)(yp-1)*W_;
  for(int xp = threadIdx.x; xp < WP_; xp += blockDim.x){
    union { ushort_t u[8]; uint4 q; } v;
    if(inrow && xp >= 1 && xp <= W_){
      int x = xp - 1;
      #pragma unroll
      for(int r = 0; r < 8; r++) v.u[r] = bf16r(src0[(size_t)r*H_*W_ + x]);
    } else {
      v.q = make_uint4(0,0,0,0);
    }
    *(uint4*)(dst + (size_t)xp*16) = v.q;
  }
}

// ---------------- prep: flows -> padded NHWC bf16 (8 ch records) ----------------
__global__ void prep_f(const float* __restrict__ init_flow, const float* __restrict__ flow_fix,
                       uint8_t* __restrict__ ws){
  int blk = blockIdx.x;
  int yp = blk % HP_;
  int b  = blk / HP_;
  uint8_t* dst = ws + FPAD_OFF + ((size_t)b*PPLANE + (size_t)yp*WP_)*16;
  for(int xp = threadIdx.x; xp < WP_; xp += blockDim.x){
    union { ushort_t u[8]; uint4 q; } v;
    if(yp >= 1 && yp <= H_ && xp >= 1 && xp <= W_){
      int y = yp - 1, x = xp - 1;
      #pragma unroll
      for(int r = 0; r < 4; r++) v.u[r]   = bf16r(init_flow[(((size_t)b*4 + r)*H_ + y)*W_ + x]);
      #pragma unroll
      for(int r = 0; r < 4; r++) v.u[4+r] = bf16r(flow_fix [(((size_t)b*4 + r)*H_ + y)*W_ + x]);
    } else {
      v.q = make_uint4(0,0,0,0);
    }
    *(uint4*)(dst + (size_t)xp*16) = v.q;
  }
}

// ---------------- prep: weights -> bf16, K-contiguous layouts ----------------
__global__ void prep_w(const float* __restrict__ w1, uint8_t* __restrict__ ws){
  int idx = blockIdx.x*256 + threadIdx.x;
  ushort_t* wt  = (ushort_t*)(ws + WT_OFF);
  ushort_t* wtf = (ushort_t*)(ws + WTF_OFF);
  if(idx < 256*9*512){
    int co  = idx / (9*512);
    int rem = idx % (9*512);
    int s   = rem / 512;
    int ci  = rem % 512;
    float v = w1[((size_t)co*520 + 8 + ci)*9 + s];
    wt[((size_t)co*9 + s)*512 + ci] = bf16r(v);
  } else {
    int i2 = idx - 256*9*512;
    if(i2 < 256*128){
      int co = i2 >> 7;
      int k  = i2 & 127;
      float v = 0.f;
      if(k < 64){ int s = k >> 3, c = k & 7; v = w1[((size_t)co*520 + c)*9 + s]; }
      else if(k < 72){ int c = k - 64;       v = w1[((size_t)co*520 + c)*9 + 8]; }
      wtf[co*128 + k] = bf16r(v);
    }
  }
}

// ---------------- fused conv3x3 + PReLU + conv1x1 + softmax + merge ----------------
// BM=224 (half-row tiles: NO y-crossing), BN=256, BK=64. 8 waves (2Mx4N), wave
// tile 112x64, acc[7][4]. HALO STRIPS: per (kk,dy) stage ONE 226-record strip
// (224 px + 1 halo each side, linear in padded memory); the 3 dx-taps are K=64
// steps reading the strip at +0/+1/+2 records. A-staging cut 3.2x.
// B: 3-buffer rotation, staged 2 steps ahead -> counted vmcnt never 0 (8/8/4).
// LDS: strips 2x32K @0, B 3x32K @65536 = 160 KiB. Epilogue overlays dead bufs.
#define BBASE  65536u
#define MASK_OFF 57344u
#define W2_OFF 98304u
#define SMEM_TOTAL 163840

__device__ __forceinline__ void gload16(const uint8_t* g, uint8_t* l){
  __builtin_amdgcn_global_load_lds((const __attribute__((address_space(1))) uint32_t*)g,
                                   (__attribute__((address_space(3))) uint32_t*)l, 16, 0, 0);
}
__device__ __forceinline__ void bar(){
  asm volatile("" ::: "memory");
  __builtin_amdgcn_s_barrier();
  asm volatile("" ::: "memory");
}
__device__ __forceinline__ void bar_lds(){
  asm volatile("s_waitcnt lgkmcnt(0)" ::: "memory");
  __builtin_amdgcn_s_barrier();
  asm volatile("" ::: "memory");
}
__device__ __forceinline__ void lgkm0(){
  asm volatile("s_waitcnt lgkmcnt(0)" ::: "memory");
}

__launch_bounds__(512, 2)
__global__ void mega(const uint8_t* __restrict__ ws, const float* __restrict__ w2,
                     const float* __restrict__ b1, const float* __restrict__ pw,
                     const float* __restrict__ b2,
                     const float* __restrict__ init_flow, const float* __restrict__ flow_fix,
                     float* __restrict__ out){
  __shared__ uint8_t smem[SMEM_TOTAL];
  const int tid = threadIdx.x;
  const int l   = tid & 63;
  const int w   = tid >> 6;
  // T1: XCD-aware bijective swizzle (1024 = 8 * 128)
  const int blk0 = blockIdx.x;
  const int blk  = (blk0 & 7)*128 + (blk0 >> 3);
  const int b   = blk / 512;
  const int wi  = blk % 512;
  const int y0  = wi >> 1;
  const int x0  = (wi & 1)*224;
  const int p0  = wi*224;                 // = y0*448 + x0

  const uint8_t* xpad = ws + XPAD_OFF;
  const uint8_t* fpad = ws + FPAD_OFF;
  const uint8_t* wt   = ws + WT_OFF;
  const uint8_t* wtf  = ws + WTF_OFF;

  // --- per-lane staging precompute (dest D = q*8192 + tid*16; swizzle keeps rec) ---
  const int base72 = (b*PPLANE + (y0 + 1)*WP_ + (x0 + 1))*16;   // pixel m=0, tap (1,1)
  uint32_t soff[4]; int f72rel[4], f73rel[4];
  #pragma unroll
  for(int q = 0; q < 4; q++){
    uint32_t D = (uint32_t)(q*8192 + tid*16);
    uint32_t rec  = D >> 7;                                 // strip record / pixel m
    uint32_t slot = ((D >> 4) & 7u) ^ (rec & 7u);           // 8ch sub-block within K=64
    soff[q] = slot*XPAD_CB_STRIDE32 + rec*16u;
    if(rec < 224u){
      int dyq = (int)slot/3, dxq = (int)slot - dyq*3;
      f72rel[q] = ((int)rec + (dyq - 1)*WP_ + (dxq - 1))*16;
    } else f72rel[q] = -base72;
    if(rec < 224u && slot == 0u) f73rel[q] = ((int)rec + WP_ + 1)*16;
    else                          f73rel[q] = -base72;      // fpad record 0 = zeros
  }
  uint32_t boff2[4], bfl[4];
  #pragma unroll
  for(int r = 0; r < 4; r++){
    uint32_t D = (uint32_t)(r*8192 + tid*16);
    uint32_t L = D ^ (((D >> 7) & 7u) << 4);
    uint32_t co = L >> 7, cib = L & 127u;
    boff2[r] = co*9216u + cib;
    bfl[r]   = co*256u + cib;
  }

  // fragment-read constants
  const int wave_m = w >> 2, wave_n = w & 3;
  const uint32_t koff = ((uint32_t)(l >> 4))*16u;
  const uint32_t swB  = ((uint32_t)(l & 7)) << 4;
  const uint32_t rb0  = (uint32_t)(wave_m*112 + (l & 15));
  const uint32_t rowBb = ((uint32_t)(wave_n*64 + (l & 15)))*128u;

  const f32x4 zero4 = {0.f, 0.f, 0.f, 0.f};
  f32x4 acc[7][4];
  #pragma unroll
  for(int i = 0; i < 7; i++)
    #pragma unroll
    for(int j = 0; j < 4; j++) acc[i][j] = zero4;

  // --- staging (wave-uniform LDS base + lane*16; 4 loads/thread always) ---
  auto stStrip = [&](int g2){                // g2 = kk2*3+dy2, 0..23
    int kk2 = g2/3, dy2 = g2 - kk2*3;
    uint32_t base = (uint32_t)(kk2*8)*XPAD_CB_STRIDE32 + (uint32_t)(b*(PPLANE*16))
                  + (uint32_t)(((y0 + dy2)*WP_ + x0)*16);
    uint8_t* la = smem + (uint32_t)(g2 & 1)*32768u + (uint32_t)(w*1024);
    #pragma unroll
    for(int q = 0; q < 4; q++) gload16(xpad + (base + soff[q]), la + q*8192);
  };
  auto stFlow = [&](int which){              // which 0/1 -> strip buf which
    uint8_t* la = smem + (uint32_t)which*32768u + (uint32_t)(w*1024);
    #pragma unroll
    for(int q = 0; q < 4; q++){
      int rel = which ? f73rel[q] : f72rel[q];
      gload16(fpad + (uint32_t)(base72 + rel), la + q*8192);
    }
  };
  auto stB = [&](int s2, int dstb){
    uint8_t* lb = smem + BBASE + (uint32_t)dstb*32768u + (uint32_t)(w*1024);
    if(s2 < 72){
      int kk2 = s2/9, tap = s2 - kk2*9;
      uint32_t stepB = (uint32_t)(tap*1024 + kk2*128);
      #pragma unroll
      for(int r = 0; r < 4; r++) gload16(wt + (boff2[r] + stepB), lb + r*8192);
    } else {
      uint32_t add = (s2 == 72) ? 0u : 128u;
      #pragma unroll
      for(int r = 0; r < 4; r++) gload16(wtf + (bfl[r] + add), lb + r*8192);
    }
  };

  // prologue: B0->buf0, strip0->buf0, B1->buf1; retire B0+strip0, leave B1
  stB(0, 0);
  stStrip(0);
  stB(1, 1);
  asm volatile("s_waitcnt vmcnt(4)" ::: "memory");
  bar();

  int kk = 0, dy = 0, dxs = 0, bb = 0;
  #pragma unroll 1
  for(int s = 0; s < 74; s++){
    const int gbuf = (s < 72) ? ((kk*3 + dy) & 1) : (s - 72);
    const uint8_t* Ab = smem + (uint32_t)gbuf*32768u;
    const uint8_t* Bb = smem + BBASE + (uint32_t)bb*32768u;
    const uint32_t rdx = (s < 72) ? (uint32_t)dxs : 0u;
    bf16x8 av[4], bv0[4], bv1[4];

    // ---- ph0: mi 0-3, kc0, + bv0; issue staging ----
    #pragma unroll
    for(int mi = 0; mi < 4; mi++){
      uint32_t rec = rb0 + (uint32_t)(mi*16) + rdx;
      av[mi] = *(const bf16x8*)(Ab + ((rec << 7) + (koff ^ ((rec & 7u) << 4))));
    }
    #pragma unroll
    for(int ni = 0; ni < 4; ni++)
      bv0[ni] = *(const bf16x8*)(Bb + (rowBb + (uint32_t)(ni*2048) + (koff ^ swB)));
    if(s < 72) stB(s + 2, (bb + 2 == 3) ? 0 : ((bb + 2 == 4) ? 1 : bb + 2));
    if(dxs == 0 && s < 73){
      int g2 = (s < 72) ? (kk*3 + dy + 1) : 25;
      if(g2 < 24)      stStrip(g2);
      else if(g2 == 24) stFlow(0);
      else              stFlow(1);
    }
    bar(); lgkm0();
    __builtin_amdgcn_s_setprio(1);
    #pragma unroll
    for(int ni = 0; ni < 4; ni++)
      #pragma unroll
      for(int mi = 0; mi < 4; mi++)
        acc[mi][ni] = __builtin_amdgcn_mfma_f32_16x16x32_bf16(av[mi], bv0[ni], acc[mi][ni], 0, 0, 0);
    __builtin_amdgcn_s_setprio(0);
    bar();

    // ---- ph1: mi 0-3, kc1, + bv1 ----
    #pragma unroll
    for(int mi = 0; mi < 4; mi++){
      uint32_t rec = rb0 + (uint32_t)(mi*16) + rdx;
      av[mi] = *(const bf16x8*)(Ab + ((rec << 7) + ((64u + koff) ^ ((rec & 7u) << 4))));
    }
    #pragma unroll
    for(int ni = 0; ni < 4; ni++)
      bv1[ni] = *(const bf16x8*)(Bb + (rowBb + (uint32_t)(ni*2048) + ((64u + koff) ^ swB)));
    bar(); lgkm0();
    __builtin_amdgcn_s_setprio(1);
    #pragma unroll
    for(int ni = 0; ni < 4; ni++)
      #pragma unroll
      for(int mi = 0; mi < 4; mi++)
        acc[mi][ni] = __builtin_amdgcn_mfma_f32_16x16x32_bf16(av[mi], bv1[ni], acc[mi][ni], 0, 0, 0);
    __builtin_amdgcn_s_setprio(0);
    bar();

    // ---- ph2: mi 4-6, kc0 (bv0 in regs) ----
    #pragma unroll
    for(int mi = 0; mi < 3; mi++){
      uint32_t rec = rb0 + (uint32_t)((mi + 4)*16) + rdx;
      av[mi] = *(const bf16x8*)(Ab + ((rec << 7) + (koff ^ ((rec & 7u) << 4))));
    }
    bar(); lgkm0();
    __builtin_amdgcn_s_setprio(1);
    #pragma unroll
    for(int ni = 0; ni < 4; ni++)
      #pragma unroll
      for(int mi = 0; mi < 3; mi++)
        acc[mi+4][ni] = __builtin_amdgcn_mfma_f32_16x16x32_bf16(av[mi], bv0[ni], acc[mi+4][ni], 0, 0, 0);
    __builtin_amdgcn_s_setprio(0);
    bar();

    // ---- ph3: mi 4-6, kc1 (bv1 in regs); counted retire ----
    #pragma unroll
    for(int mi = 0; mi < 3; mi++){
      uint32_t rec = rb0 + (uint32_t)((mi + 4)*16) + rdx;
      av[mi] = *(const bf16x8*)(Ab + ((rec << 7) + ((64u + koff) ^ ((rec & 7u) << 4))));
    }
    bar(); lgkm0();
    __builtin_amdgcn_s_setprio(1);
    #pragma unroll
    for(int ni = 0; ni < 4; ni++)
      #pragma unroll
      for(int mi = 0; mi < 3; mi++)
        acc[mi+4][ni] = __builtin_amdgcn_mfma_f32_16x16x32_bf16(av[mi], bv1[ni], acc[mi+4][ni], 0, 0, 0);
    __builtin_amdgcn_s_setprio(0);
    if(s < 72){
      if(dxs < 2) asm volatile("s_waitcnt vmcnt(8)" ::: "memory");
      else        asm volatile("s_waitcnt vmcnt(4)" ::: "memory");
    } else if(s == 72) asm volatile("s_waitcnt vmcnt(4)" ::: "memory");
    else               asm volatile("s_waitcnt vmcnt(0)" ::: "memory");
    bar();

    // increment counters
    bb = (bb == 2) ? 0 : bb + 1;
    dxs++;
    if(dxs == 3){ dxs = 0; dy++; if(dy == 3){ dy = 0; kk++; } }
  }

  // --- stage W2 (fp32 -> bf16) into LDS @W2_OFF, 512B rows, XOR-swizzled ---
  for(int e2 = tid; e2 < 48*256; e2 += 512){
    int row = e2 >> 8, k = e2 & 255;
    float f = (row < 36) ? w2[row*256 + k] : 0.f;
    uint32_t phys = ((uint32_t)(row*512 + k*2)) ^ (((uint32_t)(row & 7)) << 4);
    *(ushort_t*)(smem + W2_OFF + phys) = bf16r(f);
  }

  // --- epilogue: two passes of 112 pixels each ---
  #pragma unroll
  for(int pass = 0; pass < 2; pass++){
    if(pass) bar();
    if(wave_m == pass){
      #pragma unroll
      for(int ni = 0; ni < 4; ni++){
        int co = wave_n*64 + ni*16 + (l & 15);
        float bb1 = b1[co];
        float pp = pw[co];
        #pragma unroll
        for(int mi = 0; mi < 7; mi++){
          #pragma unroll
          for(int j = 0; j < 4; j++){
            float v = acc[mi][ni][j] + bb1;
            v = (v < 0.f) ? v*pp : v;
            int px = mi*16 + ((l >> 4) << 2) + j;     // 0..111
            uint32_t phys = ((uint32_t)(px*512 + co*2)) ^ (((uint32_t)(px & 7)) << 4);
            *(ushort_t*)(smem + phys) = bf16r(v);
          }
        }
      }
    }
    bar_lds();

    // mask GEMM: waves 0-6 -> px rows [16w,16w+16), N=48 (36 valid), K=256
    f32x4 acc2[3];
    #pragma unroll
    for(int ni = 0; ni < 3; ni++) acc2[ni] = zero4;
    if(w < 7){
      const uint32_t rowX = ((uint32_t)(16*w + (l & 15)))*512u;
      #pragma unroll
      for(int kq = 0; kq < 8; kq++){
        bf16x8 avx = *(const bf16x8*)(smem + ((rowX + (uint32_t)(kq*64) + koff) ^ swB));
        #pragma unroll
        for(int ni = 0; ni < 3; ni++){
          uint32_t rowW = ((uint32_t)(ni*16 + (l & 15)))*512u;
          bf16x8 bvx = *(const bf16x8*)(smem + W2_OFF + ((rowW + (uint32_t)(kq*64) + koff) ^ swB));
          acc2[ni] = __builtin_amdgcn_mfma_f32_16x16x32_bf16(avx, bvx, acc2[ni], 0, 0, 0);
        }
      }
    }
    bar_lds();   // all x reads done before mask overwrites smem regions
    if(w < 7){
      float* ml = (float*)(smem + MASK_OFF);
      #pragma unroll
      for(int ni = 0; ni < 3; ni++){
        int co2 = ni*16 + (l & 15);
        float bb2 = b2[co2 < 36 ? co2 : 35];
        #pragma unroll
        for(int j = 0; j < 4; j++){
          int px = 16*w + ((l >> 4) << 2) + j;
          ml[px*48 + co2] = acc2[ni][j] + bb2;
        }
      }
    }
    bar_lds();

    // softmax(2x18) + unfold-merge, 4 threads per pixel (112 px/pass -> 448 tasks)
    if(tid < 448){
      int px = tid >> 2;
      int hh = (tid >> 1) & 1;
      int c  = tid & 1;
      const float* ml = (const float*)(smem + MASK_OFF) + px*48 + hh*18;
      float mx = ml[0];
      #pragma unroll
      for(int k = 1; k < 18; k++) mx = fmaxf(mx, ml[k]);
      float e[18]; float sum = 0.f;
      #pragma unroll
      for(int k = 0; k < 18; k++){ e[k] = __expf(ml[k] - mx); sum += e[k]; }
      float inv = 1.f / sum;
      int x = x0 + pass*112 + px;
      int y = y0;
      const float* fi = init_flow + (size_t)(b*4 + 2*hh + c)*NPIX;
      const float* ff = flow_fix  + (size_t)(b*4 + 2*hh + c)*NPIX;
      float o = 0.f;
      #pragma unroll
      for(int s = 0; s < 9; s++){
        int yy = y + (s/3) - 1, xx = x + (s%3) - 1;
        if(yy >= 0 && yy < H_ && xx >= 0 && xx < W_){
          int idx = yy*W_ + xx;
          o += e[s]*fi[idx] + e[9+s]*ff[idx];
        }
      }
      out[(size_t)((b + 2*hh)*2 + c)*NPIX + y*W_ + x] = o * inv;
    }
  }
}

// ---------------- launcher ----------------
extern "C" void kernel_launch(void* const* d_in, const int* in_sizes, int n_in,
                              void* d_out, int out_size, void* d_ws, size_t ws_size,
                              hipStream_t stream) {
  const float* feature   = (const float*)d_in[0];
  const float* init_flow = (const float*)d_in[1];
  const float* flow_fix  = (const float*)d_in[2];
  const float* w1        = (const float*)d_in[3];
  const float* b1        = (const float*)d_in[4];
  const float* prelu_w   = (const float*)d_in[5];
  const float* w2        = (const float*)d_in[6];
  const float* b2        = (const float*)d_in[7];
  float* out = (float*)d_out;
  uint8_t* ws = (uint8_t*)d_ws;

  if(ws_size < WS_NEEDED) return;  // insufficient workspace -> fail visibly

  prep_x<<<64*2*HP_, 256, 0, stream>>>(feature, ws);
  prep_f<<<2*HP_,    256, 0, stream>>>(init_flow, flow_fix, ws);
  prep_w<<<4736,     256, 0, stream>>>(w1, ws);
  mega<<<1024, 512, 0, stream>>>(ws, w2, b1, prelu_w, b2, init_flow, flow_fix, out);
}

// Round 10
// 653.394 us; speedup vs baseline: 3.0210x; 1.0304x over previous
//
#include <hip/hip_runtime.h>
#include <stdint.h>
#include <stddef.h>

typedef short bf16x8 __attribute__((ext_vector_type(8)));
typedef float f32x4  __attribute__((ext_vector_type(4)));
typedef unsigned short ushort_t;

#define H_ 256
#define W_ 448
#define HP_ 258
#define WP_ 450
#define NPIX (H_*W_)
#define PPLANE (HP_*WP_)

// ---------------- workspace layout (bytes) ----------------
#define XPAD_OFF 0ull
#define XPAD_CB_STRIDE ((size_t)2*PPLANE*16)      // 3,715,200 per ci-block of 8
#define XPAD_CB_STRIDE32 (3715200u)
#define XPAD_SIZE ((size_t)64*XPAD_CB_STRIDE)     // 237,772,800
#define FPAD_OFF (XPAD_OFF + XPAD_SIZE)
#define FPAD_SIZE ((size_t)2*PPLANE*16)           // 3,715,200
#define WT_OFF   (FPAD_OFF + FPAD_SIZE)
#define WT_SIZE  ((size_t)256*9*512*2)            // 2,359,296
#define WTF_OFF  (WT_OFF + WT_SIZE)
#define WTF_SIZE ((size_t)256*128*2)              // 65,536
#define WS_NEEDED (WTF_OFF + WTF_SIZE)

__device__ __forceinline__ ushort_t bf16r(float f){
  union { float f; uint32_t u; } c; c.f = f;
  uint32_t u = c.u;
  return (ushort_t)((u + 0x7FFFu + ((u >> 16) & 1u)) >> 16);
}

// ---------------- prep: features -> padded NHWC-blocked bf16 ----------------
__global__ void prep_x(const float* __restrict__ feat, uint8_t* __restrict__ ws){
  int blk = blockIdx.x;
  int yp = blk % HP_;
  int t  = blk / HP_;
  int b  = t & 1;
  int cb = t >> 1;
  uint8_t* dst = ws + XPAD_OFF + (size_t)(cb*2 + b)*((size_t)PPLANE*16) + (size_t)yp*WP_*16;
  bool inrow = (yp >= 1 && yp <= H_);
  const float* src0 = feat + ((size_t)b*512 + (size_t)cb*8)*((size_t)H_*W_) + (size_t)(yp-1)*W_;
  for(int xp = threadIdx.x; xp < WP_; xp += blockDim.x){
    union { ushort_t u[8]; uint4 q; } v;
    if(inrow && xp >= 1 && xp <= W_){
      int x = xp - 1;
      #pragma unroll
      for(int r = 0; r < 8; r++) v.u[r] = bf16r(src0[(size_t)r*H_*W_ + x]);
    } else {
      v.q = make_uint4(0,0,0,0);
    }
    *(uint4*)(dst + (size_t)xp*16) = v.q;
  }
}

// ---------------- prep: flows -> padded NHWC bf16 (8 ch records) ----------------
__global__ void prep_f(const float* __restrict__ init_flow, const float* __restrict__ flow_fix,
                       uint8_t* __restrict__ ws){
  int blk = blockIdx.x;
  int yp = blk % HP_;
  int b  = blk / HP_;
  uint8_t* dst = ws + FPAD_OFF + ((size_t)b*PPLANE + (size_t)yp*WP_)*16;
  for(int xp = threadIdx.x; xp < WP_; xp += blockDim.x){
    union { ushort_t u[8]; uint4 q; } v;
    if(yp >= 1 && yp <= H_ && xp >= 1 && xp <= W_){
      int y = yp - 1, x = xp - 1;
      #pragma unroll
      for(int r = 0; r < 4; r++) v.u[r]   = bf16r(init_flow[(((size_t)b*4 + r)*H_ + y)*W_ + x]);
      #pragma unroll
      for(int r = 0; r < 4; r++) v.u[4+r] = bf16r(flow_fix [(((size_t)b*4 + r)*H_ + y)*W_ + x]);
    } else {
      v.q = make_uint4(0,0,0,0);
    }
    *(uint4*)(dst + (size_t)xp*16) = v.q;
  }
}

// ---------------- prep: weights -> bf16, K-contiguous layouts ----------------
__global__ void prep_w(const float* __restrict__ w1, uint8_t* __restrict__ ws){
  int idx = blockIdx.x*256 + threadIdx.x;
  ushort_t* wt  = (ushort_t*)(ws + WT_OFF);
  ushort_t* wtf = (ushort_t*)(ws + WTF_OFF);
  if(idx < 256*9*512){
    int co  = idx / (9*512);
    int rem = idx % (9*512);
    int s   = rem / 512;
    int ci  = rem % 512;
    float v = w1[((size_t)co*520 + 8 + ci)*9 + s];
    wt[((size_t)co*9 + s)*512 + ci] = bf16r(v);
  } else {
    int i2 = idx - 256*9*512;
    if(i2 < 256*128){
      int co = i2 >> 7;
      int k  = i2 & 127;
      float v = 0.f;
      if(k < 64){ int s = k >> 3, c = k & 7; v = w1[((size_t)co*520 + c)*9 + s]; }
      else if(k < 72){ int c = k - 64;       v = w1[((size_t)co*520 + c)*9 + 8]; }
      wtf[co*128 + k] = bf16r(v);
    }
  }
}

// ---------------- fused conv3x3 + PReLU + conv1x1 + softmax + merge ----------------
// BM=224 (half-row tiles, no y-crossing), BN=256, BK=64, 8 waves (2Mx4N),
// wave tile 112x64, acc[7][4]. Halo strips (per (kk,dy): one 226-rec strip serves
// 3 dx-taps). B 3-buffer rotation staged 2 ahead. NEW (this round): per-wave
// software pipeline — each phase reads the NEXT phase's fragments during the
// current MFMA cluster (no lgkm drains, compiler emits counted lgkmcnt), only
// 2 barriers/step: end-ph2 (vmcnt(N)+bar, retires next-step staging before ph3's
// cross-step read-ahead) and end-ph3.
#define BBASE  65536u
#define MASK_OFF 57344u
#define W2_OFF 98304u
#define SMEM_TOTAL 163840

__device__ __forceinline__ void gload16(const uint8_t* g, uint8_t* l){
  __builtin_amdgcn_global_load_lds((const __attribute__((address_space(1))) uint32_t*)g,
                                   (__attribute__((address_space(3))) uint32_t*)l, 16, 0, 0);
}
__device__ __forceinline__ void bar(){
  asm volatile("" ::: "memory");
  __builtin_amdgcn_s_barrier();
  asm volatile("" ::: "memory");
}
__device__ __forceinline__ void bar_lds(){
  asm volatile("s_waitcnt lgkmcnt(0)" ::: "memory");
  __builtin_amdgcn_s_barrier();
  asm volatile("" ::: "memory");
}

__launch_bounds__(512, 2)
__global__ void mega(const uint8_t* __restrict__ ws, const float* __restrict__ w2,
                     const float* __restrict__ b1, const float* __restrict__ pw,
                     const float* __restrict__ b2,
                     const float* __restrict__ init_flow, const float* __restrict__ flow_fix,
                     float* __restrict__ out){
  __shared__ uint8_t smem[SMEM_TOTAL];
  const int tid = threadIdx.x;
  const int l   = tid & 63;
  const int w   = tid >> 6;
  // T1: XCD-aware bijective swizzle (1024 = 8 * 128)
  const int blk0 = blockIdx.x;
  const int blk  = (blk0 & 7)*128 + (blk0 >> 3);
  const int b   = blk / 512;
  const int wi  = blk % 512;
  const int y0  = wi >> 1;
  const int x0  = (wi & 1)*224;

  const uint8_t* xpad = ws + XPAD_OFF;
  const uint8_t* fpad = ws + FPAD_OFF;
  const uint8_t* wt   = ws + WT_OFF;
  const uint8_t* wtf  = ws + WTF_OFF;

  // --- per-lane staging precompute (dest D = q*8192 + tid*16; swizzle keeps rec) ---
  const int base72 = (b*PPLANE + (y0 + 1)*WP_ + (x0 + 1))*16;   // pixel m=0, tap (1,1)
  uint32_t soff[4]; int f72rel[4], f73rel[4];
  #pragma unroll
  for(int q = 0; q < 4; q++){
    uint32_t D = (uint32_t)(q*8192 + tid*16);
    uint32_t rec  = D >> 7;                                 // strip record / pixel m
    uint32_t slot = ((D >> 4) & 7u) ^ (rec & 7u);           // 8ch sub-block within K=64
    soff[q] = slot*XPAD_CB_STRIDE32 + rec*16u;
    if(rec < 224u){
      int dyq = (int)slot/3, dxq = (int)slot - dyq*3;
      f72rel[q] = ((int)rec + (dyq - 1)*WP_ + (dxq - 1))*16;
    } else f72rel[q] = -base72;
    if(rec < 224u && slot == 0u) f73rel[q] = ((int)rec + WP_ + 1)*16;
    else                          f73rel[q] = -base72;      // fpad record 0 = zeros
  }
  uint32_t boff2[4], bfl[4];
  #pragma unroll
  for(int r = 0; r < 4; r++){
    uint32_t D = (uint32_t)(r*8192 + tid*16);
    uint32_t L = D ^ (((D >> 7) & 7u) << 4);
    uint32_t co = L >> 7, cib = L & 127u;
    boff2[r] = co*9216u + cib;
    bfl[r]   = co*256u + cib;
  }

  // fragment-read constants
  const int wave_m = w >> 2, wave_n = w & 3;
  const uint32_t koff = ((uint32_t)(l >> 4))*16u;
  const uint32_t swB  = ((uint32_t)(l & 7)) << 4;
  const uint32_t rb0  = (uint32_t)(wave_m*112 + (l & 15));
  const uint32_t rowBb = ((uint32_t)(wave_n*64 + (l & 15)))*128u;

  const f32x4 zero4 = {0.f, 0.f, 0.f, 0.f};
  f32x4 acc[7][4];
  #pragma unroll
  for(int i = 0; i < 7; i++)
    #pragma unroll
    for(int j = 0; j < 4; j++) acc[i][j] = zero4;

  // --- staging (wave-uniform LDS base + lane*16; 4 loads/thread always) ---
  auto stStrip = [&](int g2){                // g2 = unit index 0..23 -> buf g2&1
    int kk2 = g2/3, dy2 = g2 - kk2*3;
    uint32_t base = (uint32_t)(kk2*8)*XPAD_CB_STRIDE32 + (uint32_t)(b*(PPLANE*16))
                  + (uint32_t)(((y0 + dy2)*WP_ + x0)*16);
    uint8_t* la = smem + (uint32_t)(g2 & 1)*32768u + (uint32_t)(w*1024);
    #pragma unroll
    for(int q = 0; q < 4; q++) gload16(xpad + (base + soff[q]), la + q*8192);
  };
  auto stFlow = [&](int which){              // which 0/1 -> strip buf which
    uint8_t* la = smem + (uint32_t)which*32768u + (uint32_t)(w*1024);
    #pragma unroll
    for(int q = 0; q < 4; q++){
      int rel = which ? f73rel[q] : f72rel[q];
      gload16(fpad + (uint32_t)(base72 + rel), la + q*8192);
    }
  };
  auto stB = [&](int s2, int dstb){
    uint8_t* lb = smem + BBASE + (uint32_t)dstb*32768u + (uint32_t)(w*1024);
    if(s2 < 72){
      int kk2 = s2/9, tap = s2 - kk2*9;
      uint32_t stepB = (uint32_t)(tap*1024 + kk2*128);
      #pragma unroll
      for(int r = 0; r < 4; r++) gload16(wt + (boff2[r] + stepB), lb + r*8192);
    } else {
      uint32_t add = (s2 == 72) ? 0u : 128u;
      #pragma unroll
      for(int r = 0; r < 4; r++) gload16(wtf + (bfl[r] + add), lb + r*8192);
    }
  };
  auto stA_next = [&](int s2){               // stage A for unit s2/3 + 1
    int nxt = s2/3 + 1;
    if(nxt < 24)       stStrip(nxt);
    else if(nxt == 24) stFlow(0);
    else               stFlow(1);
  };

  // fragment readers
  auto rdA = [&](const uint8_t* Ab_, uint32_t rec, uint32_t kc64) -> bf16x8 {
    return *(const bf16x8*)(Ab_ + ((rec << 7) + ((kc64 + koff) ^ ((rec & 7u) << 4))));
  };
  auto rdB = [&](const uint8_t* Bb_, int ni, uint32_t kc64) -> bf16x8 {
    return *(const bf16x8*)(Bb_ + (rowBb + (uint32_t)(ni*2048) + ((kc64 + koff) ^ swB)));
  };

  bf16x8 avX[4], avY[4], bv0[4], bv1[4];

  // prologue: B0->Bbuf0, strip0->Abuf0, B1->Bbuf1; retire B0+strip0 (leave B1)
  stB(0, 0);
  stStrip(0);
  stB(1, 1);
  asm volatile("s_waitcnt vmcnt(4)" ::: "memory");
  bar();
  // pre-read step0 ph0 fragments
  #pragma unroll
  for(int mi = 0; mi < 4; mi++) avX[mi] = rdA(smem, rb0 + (uint32_t)(mi*16), 0u);
  #pragma unroll
  for(int ni = 0; ni < 4; ni++) bv0[ni] = rdB(smem + BBASE, ni, 0u);

  #pragma unroll 1
  for(int s = 0; s < 74; s++){
    const int gbuf = (s < 72) ? ((s/3) & 1) : (s - 72);
    const uint8_t* Ab = smem + (uint32_t)gbuf*32768u;
    const uint8_t* Bb = smem + BBASE + (uint32_t)(s % 3)*32768u;
    const uint32_t rdx = (s < 72) ? (uint32_t)(s % 3) : 0u;

    // ---- ph0: MFMA(avX,bv0)->acc[0..3]; read avY(r0-3,kc1)+bv1; issue staging ----
    #pragma unroll
    for(int mi = 0; mi < 4; mi++) avY[mi] = rdA(Ab, rb0 + (uint32_t)(mi*16) + rdx, 64u);
    #pragma unroll
    for(int ni = 0; ni < 4; ni++) bv1[ni] = rdB(Bb, ni, 64u);
    if(s < 72) stB(s + 2, (s + 2) % 3);
    if((s % 3) == 0 && s < 73) stA_next(s);
    __builtin_amdgcn_s_setprio(1);
    #pragma unroll
    for(int ni = 0; ni < 4; ni++)
      #pragma unroll
      for(int mi = 0; mi < 4; mi++)
        acc[mi][ni] = __builtin_amdgcn_mfma_f32_16x16x32_bf16(avX[mi], bv0[ni], acc[mi][ni], 0, 0, 0);
    __builtin_amdgcn_s_setprio(0);

    // ---- ph1: MFMA(avY,bv1)->acc[0..3]; read avX(r4-6,kc0) ----
    #pragma unroll
    for(int mi = 0; mi < 3; mi++) avX[mi] = rdA(Ab, rb0 + (uint32_t)((mi+4)*16) + rdx, 0u);
    __builtin_amdgcn_s_setprio(1);
    #pragma unroll
    for(int ni = 0; ni < 4; ni++)
      #pragma unroll
      for(int mi = 0; mi < 4; mi++)
        acc[mi][ni] = __builtin_amdgcn_mfma_f32_16x16x32_bf16(avY[mi], bv1[ni], acc[mi][ni], 0, 0, 0);
    __builtin_amdgcn_s_setprio(0);

    // ---- ph2: MFMA(avX[0..2],bv0)->acc[4..6]; read avY(r4-6,kc1); vmcnt(N)+bar ----
    #pragma unroll
    for(int mi = 0; mi < 3; mi++) avY[mi] = rdA(Ab, rb0 + (uint32_t)((mi+4)*16) + rdx, 64u);
    __builtin_amdgcn_s_setprio(1);
    #pragma unroll
    for(int ni = 0; ni < 4; ni++)
      #pragma unroll
      for(int mi = 0; mi < 3; mi++)
        acc[mi+4][ni] = __builtin_amdgcn_mfma_f32_16x16x32_bf16(avX[mi], bv0[ni], acc[mi+4][ni], 0, 0, 0);
    __builtin_amdgcn_s_setprio(0);
    if((s % 3) == 0){
      if(s < 72) asm volatile("s_waitcnt vmcnt(8)" ::: "memory");
      else       asm volatile("s_waitcnt vmcnt(0)" ::: "memory");
    } else {
      asm volatile("s_waitcnt vmcnt(4)" ::: "memory");
    }
    bar();

    // ---- ph3: MFMA(avY[0..2],bv1)->acc[4..6]; read-ahead next step's avX,bv0; bar ----
    if(s < 73){
      const int s1 = s + 1;
      const int gbuf1 = (s1 < 72) ? ((s1/3) & 1) : (s1 - 72);
      const uint8_t* Ab1 = smem + (uint32_t)gbuf1*32768u;
      const uint8_t* Bb1 = smem + BBASE + (uint32_t)(s1 % 3)*32768u;
      const uint32_t rdx1 = (s1 < 72) ? (uint32_t)(s1 % 3) : 0u;
      #pragma unroll
      for(int mi = 0; mi < 4; mi++) avX[mi] = rdA(Ab1, rb0 + (uint32_t)(mi*16) + rdx1, 0u);
      #pragma unroll
      for(int ni = 0; ni < 4; ni++) bv0[ni] = rdB(Bb1, ni, 0u);
    }
    __builtin_amdgcn_s_setprio(1);
    #pragma unroll
    for(int ni = 0; ni < 4; ni++)
      #pragma unroll
      for(int mi = 0; mi < 3; mi++)
        acc[mi+4][ni] = __builtin_amdgcn_mfma_f32_16x16x32_bf16(avY[mi], bv1[ni], acc[mi+4][ni], 0, 0, 0);
    __builtin_amdgcn_s_setprio(0);
    bar();
  }

  // --- stage W2 (fp32 -> bf16) into LDS @W2_OFF, 512B rows, XOR-swizzled ---
  for(int e2 = tid; e2 < 48*256; e2 += 512){
    int row = e2 >> 8, k = e2 & 255;
    float f = (row < 36) ? w2[row*256 + k] : 0.f;
    uint32_t phys = ((uint32_t)(row*512 + k*2)) ^ (((uint32_t)(row & 7)) << 4);
    *(ushort_t*)(smem + W2_OFF + phys) = bf16r(f);
  }

  // --- epilogue: two passes of 112 pixels each ---
  #pragma unroll
  for(int pass = 0; pass < 2; pass++){
    if(pass) bar();
    if(wave_m == pass){
      #pragma unroll
      for(int ni = 0; ni < 4; ni++){
        int co = wave_n*64 + ni*16 + (l & 15);
        float bb1 = b1[co];
        float pp = pw[co];
        #pragma unroll
        for(int mi = 0; mi < 7; mi++){
          #pragma unroll
          for(int j = 0; j < 4; j++){
            float v = acc[mi][ni][j] + bb1;
            v = (v < 0.f) ? v*pp : v;
            int px = mi*16 + ((l >> 4) << 2) + j;     // 0..111
            uint32_t phys = ((uint32_t)(px*512 + co*2)) ^ (((uint32_t)(px & 7)) << 4);
            *(ushort_t*)(smem + phys) = bf16r(v);
          }
        }
      }
    }
    bar_lds();

    // mask GEMM: waves 0-6 -> px rows [16w,16w+16), N=48 (36 valid), K=256
    f32x4 acc2[3];
    #pragma unroll
    for(int ni = 0; ni < 3; ni++) acc2[ni] = zero4;
    if(w < 7){
      const uint32_t rowX = ((uint32_t)(16*w + (l & 15)))*512u;
      #pragma unroll
      for(int kq = 0; kq < 8; kq++){
        bf16x8 avx = *(const bf16x8*)(smem + ((rowX + (uint32_t)(kq*64) + koff) ^ swB));
        #pragma unroll
        for(int ni = 0; ni < 3; ni++){
          uint32_t rowW = ((uint32_t)(ni*16 + (l & 15)))*512u;
          bf16x8 bvx = *(const bf16x8*)(smem + W2_OFF + ((rowW + (uint32_t)(kq*64) + koff) ^ swB));
          acc2[ni] = __builtin_amdgcn_mfma_f32_16x16x32_bf16(avx, bvx, acc2[ni], 0, 0, 0);
        }
      }
    }
    bar_lds();   // all x reads done before mask overwrites smem regions
    if(w < 7){
      float* ml = (float*)(smem + MASK_OFF);
      #pragma unroll
      for(int ni = 0; ni < 3; ni++){
        int co2 = ni*16 + (l & 15);
        float bb2 = b2[co2 < 36 ? co2 : 35];
        #pragma unroll
        for(int j = 0; j < 4; j++){
          int px = 16*w + ((l >> 4) << 2) + j;
          ml[px*48 + co2] = acc2[ni][j] + bb2;
        }
      }
    }
    bar_lds();

    // softmax(2x18) + unfold-merge, 4 threads per pixel (112 px/pass -> 448 tasks)
    if(tid < 448){
      int px = tid >> 2;
      int hh = (tid >> 1) & 1;
      int c  = tid & 1;
      const float* ml = (const float*)(smem + MASK_OFF) + px*48 + hh*18;
      float mx = ml[0];
      #pragma unroll
      for(int k = 1; k < 18; k++) mx = fmaxf(mx, ml[k]);
      float e[18]; float sum = 0.f;
      #pragma unroll
      for(int k = 0; k < 18; k++){ e[k] = __expf(ml[k] - mx); sum += e[k]; }
      float inv = 1.f / sum;
      int x = x0 + pass*112 + px;
      int y = y0;
      const float* fi = init_flow + (size_t)(b*4 + 2*hh + c)*NPIX;
      const float* ff = flow_fix  + (size_t)(b*4 + 2*hh + c)*NPIX;
      float o = 0.f;
      #pragma unroll
      for(int s = 0; s < 9; s++){
        int yy = y + (s/3) - 1, xx = x + (s%3) - 1;
        if(yy >= 0 && yy < H_ && xx >= 0 && xx < W_){
          int idx = yy*W_ + xx;
          o += e[s]*fi[idx] + e[9+s]*ff[idx];
        }
      }
      out[(size_t)((b + 2*hh)*2 + c)*NPIX + y*W_ + x] = o * inv;
    }
  }
}

// ---------------- launcher ----------------
extern "C" void kernel_launch(void* const* d_in, const int* in_sizes, int n_in,
                              void* d_out, int out_size, void* d_ws, size_t ws_size,
                              hipStream_t stream) {
  const float* feature   = (const float*)d_in[0];
  const float* init_flow = (const float*)d_in[1];
  const float* flow_fix  = (const float*)d_in[2];
  const float* w1        = (const float*)d_in[3];
  const float* b1        = (const float*)d_in[4];
  const float* prelu_w   = (const float*)d_in[5];
  const float* w2        = (const float*)d_in[6];
  const float* b2        = (const float*)d_in[7];
  float* out = (float*)d_out;
  uint8_t* ws = (uint8_t*)d_ws;

  if(ws_size < WS_NEEDED) return;  // insufficient workspace -> fail visibly

  prep_x<<<64*2*HP_, 256, 0, stream>>>(feature, ws);
  prep_f<<<2*HP_,    256, 0, stream>>>(init_flow, flow_fix, ws);
  prep_w<<<4736,     256, 0, stream>>>(w1, ws);
  mega<<<1024, 512, 0, stream>>>(ws, w2, b1, prelu_w, b2, init_flow, flow_fix, out);
}